// Round 5
// baseline (801.043 us; speedup 1.0000x reference)
//
#include <hip/hip_runtime.h>
#include <hip/hip_fp16.h>
#include <math.h>

// ---------------------------------------------------------------------------
// ADCGNN amazon: N=50000, E=1.6M, IN=128, H=64, C=2, K=3
//
// R5: fp16 gather rows -> gather not byte-bound.
// R6: 8-lane retile -> not instruction-bound. REVERTED.
// R7: wave-private LDS + readlane GEMVs: tail 142->120us, VALU-bound dense.
// R8: algebraic expansion (precompute P_x=x@Wf1top, R_x=x@W3): correct
//     (absmax 1.2e-4) but precompute kernels had 782 waves for 1024 SIMDs
//     (occ 8.8%, VALU 12%) -> 488us. Parallelism bug, not algebra bug.
// R9 (this round): same expansion, quarter-split precompute: 4 thr/node
//     (3125 waves), no LDS/barriers, shfl width-4 reductions in final.
//     dense2res reverted to R3 form.
//
// Pipeline:
//   build: bucket_count -> bucket_scan -> bucket_scatter -> csr_build
//   dense1:     h1 = relu(X@W1+b1)
//   dense2res:  h, hs=f16(h*dinv), res, th=h.Wattn            (R3 form)
//   dense_post: Ph=h@Wf1top, QhB=h@Wf1bot+bf1, Rh=h@W3, Rresb=0.8res@W3+b3
//   spmm1:      u1, u1s=f16(u1*dinv), ta
//   dense_u1q:  Pu1=u1@Wf1top, Ru1=u1@W3
//   spmm2:      u2s=f16(u2), tb                               (pure gather)
//   final:      4thr/node: Pu2,Ru2 + softmax + fusion + logits
// ---------------------------------------------------------------------------

#define BSHIFT 7
#define BNODES 128
#define BMAX   512
#define EPT    32
#define CHUNK  (256 * EPT)
#define CAP    8192

__device__ __forceinline__ void fma4(float4& acc, float s, const float4 w) {
    acc.x += s * w.x; acc.y += s * w.y; acc.z += s * w.z; acc.w += s * w.w;
}

__device__ __forceinline__ float2 pack_half4(float x, float y, float z, float w) {
    union { __half2 h[2]; float2 f; } u;
    u.h[0] = __floats2half2_rn(x, y);
    u.h[1] = __floats2half2_rn(z, w);
    return u.f;
}

__device__ __forceinline__ void acch4(float4& a, float2 p) {
    union { float2 f; __half2 h[2]; } u; u.f = p;
    float2 lo = __half22float2(u.h[0]);
    float2 hi = __half22float2(u.h[1]);
    a.x += lo.x; a.y += lo.y; a.z += hi.x; a.w += hi.y;
}

// quarter-GEMV: acc[0..3] (16 outputs at columns q*16..q*16+15) += row @ W
// row = 64 fp32 (16 float4), W row-major 64x64.
__device__ __forceinline__ void qgemv64(const float4* __restrict__ src4,
                                        const float* __restrict__ W, int q,
                                        float4* acc) {
    const float4* W4 = (const float4*)W;
    #pragma unroll 1
    for (int kc = 0; kc < 16; kc++) {
        float4 a = src4[kc];
        const float4* w0 = W4 + (4 * kc + 0) * 16 + q * 4;
        const float4* w1 = W4 + (4 * kc + 1) * 16 + q * 4;
        const float4* w2 = W4 + (4 * kc + 2) * 16 + q * 4;
        const float4* w3 = W4 + (4 * kc + 3) * 16 + q * 4;
        #pragma unroll
        for (int j = 0; j < 4; j++) {
            fma4(acc[j], a.x, w0[j]);
            fma4(acc[j], a.y, w1[j]);
            fma4(acc[j], a.z, w2[j]);
            fma4(acc[j], a.w, w3[j]);
        }
    }
}

// quarter-GEMV with f16 row (8 float4 = 64 halves)
__device__ __forceinline__ void qgemv64h(const float4* __restrict__ row8,
                                         const float* __restrict__ W, int q,
                                         float4* acc) {
    const float4* W4 = (const float4*)W;
    #pragma unroll 1
    for (int t8 = 0; t8 < 8; t8++) {
        union { float4 f; __half2 h[4]; } u; u.f = row8[t8];
        #pragma unroll
        for (int e = 0; e < 4; e++) {
            float2 v = __half22float2(u.h[e]);
            int k0 = t8 * 8 + 2 * e;
            const float4* wa = W4 + k0 * 16 + q * 4;
            const float4* wb = W4 + (k0 + 1) * 16 + q * 4;
            #pragma unroll
            for (int j = 0; j < 4; j++) {
                fma4(acc[j], v.x, wa[j]);
                fma4(acc[j], v.y, wb[j]);
            }
        }
    }
}

// ----------------------------- graph build ---------------------------------

__global__ __launch_bounds__(256) void bucket_count_k(const int* __restrict__ dst,
                                                      int* __restrict__ bucketCount,
                                                      int E, int B) {
    __shared__ int cnt[BMAX];
    for (int i = threadIdx.x; i < B; i += 256) cnt[i] = 0;
    __syncthreads();
    int base = blockIdx.x * CHUNK;
    #pragma unroll
    for (int t = 0; t < EPT; t++) {
        int e = base + t * 256 + threadIdx.x;
        if (e < E) atomicAdd(&cnt[dst[e] >> BSHIFT], 1);
    }
    __syncthreads();
    for (int i = threadIdx.x; i < B; i += 256)
        if (cnt[i] > 0) atomicAdd(&bucketCount[i], cnt[i]);
}

__global__ __launch_bounds__(64) void bucket_scan_k(const int* __restrict__ bucketCount,
                                                    int* __restrict__ bucketPtr,
                                                    int* __restrict__ bucketCursor,
                                                    int* __restrict__ rowPtr,
                                                    int B, int N, int E) {
    int lane = threadIdx.x;
    const int PT = (BMAX + 63) / 64;
    int v[PT]; int s = 0;
    #pragma unroll
    for (int t = 0; t < PT; t++) {
        int i = lane * PT + t;
        v[t] = (i < B) ? bucketCount[i] : 0;
        s += v[t];
    }
    int x = s;
    #pragma unroll
    for (int off = 1; off < 64; off <<= 1) {
        int y = __shfl_up(x, off, 64);
        if (lane >= off) x += y;
    }
    int run = x - s;
    #pragma unroll
    for (int t = 0; t < PT; t++) {
        int i = lane * PT + t;
        if (i < B) { bucketPtr[i] = run; bucketCursor[i] = run; }
        run += v[t];
    }
    if (lane == 63) bucketPtr[B] = x;
    if (lane == 0) rowPtr[N] = E;
}

__global__ __launch_bounds__(256) void bucket_scatter_k(const int* __restrict__ src,
                                                        const int* __restrict__ dst,
                                                        int* __restrict__ bucketCursor,
                                                        int* __restrict__ ebuf,
                                                        int E, int B) {
    __shared__ int cnt[BMAX];
    __shared__ int base[BMAX];
    __shared__ int cur[BMAX];
    for (int i = threadIdx.x; i < B; i += 256) { cnt[i] = 0; cur[i] = 0; }
    __syncthreads();
    int cbase = blockIdx.x * CHUNK;
    int d[EPT];
    #pragma unroll
    for (int t = 0; t < EPT; t++) {
        int e = cbase + t * 256 + threadIdx.x;
        d[t] = (e < E) ? dst[e] : -1;
        if (d[t] >= 0) atomicAdd(&cnt[d[t] >> BSHIFT], 1);
    }
    __syncthreads();
    for (int i = threadIdx.x; i < B; i += 256)
        if (cnt[i] > 0) base[i] = atomicAdd(&bucketCursor[i], cnt[i]);
    __syncthreads();
    #pragma unroll
    for (int t = 0; t < EPT; t++) {
        int e = cbase + t * 256 + threadIdx.x;
        if (d[t] >= 0) {
            int b = d[t] >> BSHIFT;
            int c = atomicAdd(&cur[b], 1);
            int pack = (src[e] & 0xFFFF) | ((d[t] & (BNODES - 1)) << 16);
            ebuf[base[b] + c] = pack;
        }
    }
}

__global__ __launch_bounds__(256) void csr_build_k(const int* __restrict__ ebuf,
                                                   const int* __restrict__ bucketPtr,
                                                   int* __restrict__ rowPtr,
                                                   float* __restrict__ dinv,
                                                   int* __restrict__ srcSorted,
                                                   int N) {
    __shared__ int deg[BNODES];
    __shared__ int rp[BNODES + 1];
    __shared__ int cur[BNODES];
    __shared__ int stage[CAP];
    int b = blockIdx.x;
    int nodeBase = b << BSHIFT;
    int nNodes = min(BNODES, N - nodeBase);
    int eBase = bucketPtr[b];
    int eCnt = bucketPtr[b + 1] - eBase;
    for (int i = threadIdx.x; i < BNODES; i += 256) deg[i] = 0;
    __syncthreads();
    for (int i = threadIdx.x; i < eCnt; i += 256)
        atomicAdd(&deg[(ebuf[eBase + i] >> 16) & (BNODES - 1)], 1);
    __syncthreads();
    if (threadIdx.x < 64) {
        int lane = threadIdx.x;
        int d0 = deg[2 * lane], d1 = deg[2 * lane + 1];
        int s = d0 + d1;
        int x = s;
        #pragma unroll
        for (int off = 1; off < 64; off <<= 1) {
            int y = __shfl_up(x, off, 64);
            if (lane >= off) x += y;
        }
        int ex = x - s;
        rp[2 * lane] = ex;
        rp[2 * lane + 1] = ex + d0;
        cur[2 * lane] = ex;
        cur[2 * lane + 1] = ex + d0;
        if (lane == 63) rp[BNODES] = x;
    }
    __syncthreads();
    for (int j = threadIdx.x; j < nNodes; j += 256) {
        rowPtr[nodeBase + j] = eBase + rp[j];
        int dg = deg[j];
        dinv[nodeBase + j] = rsqrtf((float)(dg > 1 ? dg : 1));
    }
    if (eCnt <= CAP) {
        for (int i = threadIdx.x; i < eCnt; i += 256) {
            int p = ebuf[eBase + i];
            int ld = (p >> 16) & (BNODES - 1);
            int pos = atomicAdd(&cur[ld], 1);
            stage[pos] = p & 0xFFFF;
        }
        __syncthreads();
        for (int i = threadIdx.x; i < eCnt; i += 256)
            srcSorted[eBase + i] = stage[i];
    } else {
        for (int i = threadIdx.x; i < eCnt; i += 256) {
            int p = ebuf[eBase + i];
            int ld = (p >> 16) & (BNODES - 1);
            int pos = atomicAdd(&cur[ld], 1);
            srcSorted[eBase + pos] = p & 0xFFFF;
        }
    }
}

// ----------------------------- dense1 --------------------------------------

#define D1_BLK 128
#define D1_PAD 68

__global__ __launch_bounds__(D1_BLK) void dense1_k(const float* __restrict__ Xg,
                                                   const float* __restrict__ W1,
                                                   const float* __restrict__ b1,
                                                   float* __restrict__ h1, int N) {
    __shared__ float lds[D1_BLK * D1_PAD];
    int n0 = blockIdx.x * D1_BLK;
    int n = n0 + threadIdx.x;
    bool act = (n < N);
    const float4* W = (const float4*)W1;
    const float4* B = (const float4*)b1;
    float4 acc[16];
    #pragma unroll
    for (int j = 0; j < 16; j++) acc[j] = B[j];
    if (act) {
        const float4* X = (const float4*)Xg + (size_t)n * 32;
        float4 a = X[0];
        #pragma unroll 1
        for (int kc = 0; kc < 32; kc++) {
            float4 an = a;
            if (kc + 1 < 32) an = X[kc + 1];
            const float4* wrow = W + kc * 64;
            #pragma unroll
            for (int j = 0; j < 16; j++) {
                fma4(acc[j], a.x, wrow[j]);
                fma4(acc[j], a.y, wrow[16 + j]);
                fma4(acc[j], a.z, wrow[32 + j]);
                fma4(acc[j], a.w, wrow[48 + j]);
            }
            a = an;
        }
    }
    float* myrow = &lds[threadIdx.x * D1_PAD];
    #pragma unroll
    for (int j = 0; j < 16; j++) {
        float4 v = acc[j];
        *(float4*)&myrow[4 * j] = make_float4(fmaxf(v.x, 0.f), fmaxf(v.y, 0.f),
                                              fmaxf(v.z, 0.f), fmaxf(v.w, 0.f));
    }
    __syncthreads();
    float4* o4 = (float4*)h1;
    #pragma unroll
    for (int r = 0; r < 16; r++) {
        int idx = r * D1_BLK + threadIdx.x;
        int row = idx >> 4, col = idx & 15;
        int gn = n0 + row;
        if (gn < N) o4[(size_t)gn * 16 + col] = *(float4*)&lds[row * D1_PAD + col * 4];
    }
}

// ----------------------------- dense2res (R3 form) --------------------------

#define D2_BLK 128
#define D2_PAD 68

__global__ __launch_bounds__(D2_BLK) void dense2res_k(const float* __restrict__ h1,
                                                      const float* __restrict__ W2,
                                                      const float* __restrict__ b2,
                                                      const float* __restrict__ Wres,
                                                      const float* __restrict__ bres,
                                                      const float* __restrict__ Wattn,
                                                      const float* __restrict__ dinv,
                                                      float* __restrict__ hg,
                                                      float2* __restrict__ hs2,
                                                      float* __restrict__ resg,
                                                      float* __restrict__ thv, int N) {
    __shared__ float lds[D2_BLK * D2_PAD];
    int n0 = blockIdx.x * D2_BLK;
    int n = n0 + threadIdx.x;
    bool act = (n < N);
    const float4* W = (const float4*)W2;
    const float4* B = (const float4*)b2;
    float4 acc[16];
    #pragma unroll
    for (int j = 0; j < 16; j++) acc[j] = B[j];
    if (act) {
        const float4* X = (const float4*)h1 + (size_t)n * 16;
        float4 a = X[0];
        #pragma unroll 1
        for (int kc = 0; kc < 16; kc++) {
            float4 an = a;
            if (kc + 1 < 16) an = X[kc + 1];
            const float4* wrow = W + kc * 64;
            #pragma unroll
            for (int j = 0; j < 16; j++) {
                fma4(acc[j], a.x, wrow[j]);
                fma4(acc[j], a.y, wrow[16 + j]);
                fma4(acc[j], a.z, wrow[32 + j]);
                fma4(acc[j], a.w, wrow[48 + j]);
            }
            a = an;
        }
    }
    const float4* Wa = (const float4*)Wattn;
    float th = 0.f;
    float* myrow = &lds[threadIdx.x * D2_PAD];
    #pragma unroll
    for (int j = 0; j < 16; j++) {
        float4 v = acc[j];
        v.x = fmaxf(v.x, 0.f); v.y = fmaxf(v.y, 0.f);
        v.z = fmaxf(v.z, 0.f); v.w = fmaxf(v.w, 0.f);
        acc[j] = v;
        *(float4*)&myrow[4 * j] = v;
        float4 w = Wa[j];
        th += v.x * w.x + v.y * w.y + v.z * w.z + v.w * w.w;
    }
    if (act) thv[n] = th;
    __syncthreads();
    float4* h4 = (float4*)hg;
    #pragma unroll
    for (int r = 0; r < 16; r++) {
        int idx = r * D2_BLK + threadIdx.x;
        int row = idx >> 4, col = idx & 15;
        int gn = n0 + row;
        if (gn < N) {
            float4 v = *(float4*)&lds[row * D2_PAD + col * 4];
            h4[(size_t)gn * 16 + col] = v;
            float di = dinv[gn];
            hs2[(size_t)gn * 16 + col] =
                pack_half4(v.x * di, v.y * di, v.z * di, v.w * di);
        }
    }
    // res = h @ Wres + bres (h still in regs)
    const float4* WR = (const float4*)Wres;
    const float4* BR = (const float4*)bres;
    float4 acc2[16];
    #pragma unroll
    for (int j = 0; j < 16; j++) acc2[j] = BR[j];
    #pragma unroll 1
    for (int kc = 0; kc < 16; kc++) {
        float4 a2 = acc[kc];
        const float4* wrow = WR + kc * 64;
        #pragma unroll
        for (int j = 0; j < 16; j++) {
            fma4(acc2[j], a2.x, wrow[j]);
            fma4(acc2[j], a2.y, wrow[16 + j]);
            fma4(acc2[j], a2.z, wrow[32 + j]);
            fma4(acc2[j], a2.w, wrow[48 + j]);
        }
    }
    __syncthreads();
    #pragma unroll
    for (int j = 0; j < 16; j++) *(float4*)&myrow[4 * j] = acc2[j];
    __syncthreads();
    float4* r4 = (float4*)resg;
    #pragma unroll
    for (int r = 0; r < 16; r++) {
        int idx = r * D2_BLK + threadIdx.x;
        int row = idx >> 4, col = idx & 15;
        int gn = n0 + row;
        if (gn < N) r4[(size_t)gn * 16 + col] = *(float4*)&lds[row * D2_PAD + col * 4];
    }
}

// ----------------------------- dense_post (4 thr/node) ----------------------
// Ph = h@Wf1top; QhB = h@Wf1bot + bf1; Rh = h@W3; Rresb = 0.8*res@W3 + b3.

__global__ __launch_bounds__(256) void dense_post_k(const float* __restrict__ hg,
                                                    const float* __restrict__ resg,
                                                    const float* __restrict__ Wf1,
                                                    const float* __restrict__ bf1,
                                                    const float* __restrict__ W3,
                                                    const float* __restrict__ b3,
                                                    float* __restrict__ Ph,
                                                    float* __restrict__ QhB,
                                                    float* __restrict__ Rh,
                                                    float* __restrict__ Rresb, int N) {
    int t = blockIdx.x * 256 + threadIdx.x;
    int n = t >> 2, q = t & 3;
    if (n >= N) return;
    const float4* hr = (const float4*)hg + (size_t)n * 16;
    float4 acc[4];
    // Ph
    #pragma unroll
    for (int j = 0; j < 4; j++) acc[j] = make_float4(0.f, 0.f, 0.f, 0.f);
    qgemv64(hr, Wf1, q, acc);
    {
        float4* o = (float4*)Ph + (size_t)n * 16 + q * 4;
        #pragma unroll
        for (int j = 0; j < 4; j++) o[j] = acc[j];
    }
    // QhB
    #pragma unroll
    for (int j = 0; j < 4; j++) acc[j] = make_float4(0.f, 0.f, 0.f, 0.f);
    qgemv64(hr, Wf1 + 4096, q, acc);
    {
        const float4* bb = (const float4*)bf1 + q * 4;
        float4* o = (float4*)QhB + (size_t)n * 16 + q * 4;
        #pragma unroll
        for (int j = 0; j < 4; j++) {
            float4 b = bb[j];
            o[j] = make_float4(acc[j].x + b.x, acc[j].y + b.y,
                               acc[j].z + b.z, acc[j].w + b.w);
        }
    }
    // Rh
    #pragma unroll
    for (int j = 0; j < 4; j++) acc[j] = make_float4(0.f, 0.f, 0.f, 0.f);
    qgemv64(hr, W3, q, acc);
    {
        float4* o = (float4*)Rh + (size_t)n * 16 + q * 4;
        #pragma unroll
        for (int j = 0; j < 4; j++) o[j] = acc[j];
    }
    // Rresb
    const float4* rr = (const float4*)resg + (size_t)n * 16;
    #pragma unroll
    for (int j = 0; j < 4; j++) acc[j] = make_float4(0.f, 0.f, 0.f, 0.f);
    qgemv64(rr, W3, q, acc);
    {
        const float4* bb = (const float4*)b3 + q * 4;
        float4* o = (float4*)Rresb + (size_t)n * 16 + q * 4;
        #pragma unroll
        for (int j = 0; j < 4; j++) {
            float4 b = bb[j];
            o[j] = make_float4(0.8f * acc[j].x + b.x, 0.8f * acc[j].y + b.y,
                               0.8f * acc[j].z + b.z, 0.8f * acc[j].w + b.w);
        }
    }
}

// ----------------------------- dense_u1q (4 thr/node) -----------------------

__global__ __launch_bounds__(256) void dense_u1q_k(const float* __restrict__ u1,
                                                   const float* __restrict__ Wf1,
                                                   const float* __restrict__ W3,
                                                   float* __restrict__ Pu1,
                                                   float* __restrict__ Ru1, int N) {
    int t = blockIdx.x * 256 + threadIdx.x;
    int n = t >> 2, q = t & 3;
    if (n >= N) return;
    const float4* ur = (const float4*)u1 + (size_t)n * 16;
    float4 acc[4];
    #pragma unroll
    for (int j = 0; j < 4; j++) acc[j] = make_float4(0.f, 0.f, 0.f, 0.f);
    qgemv64(ur, Wf1, q, acc);
    {
        float4* o = (float4*)Pu1 + (size_t)n * 16 + q * 4;
        #pragma unroll
        for (int j = 0; j < 4; j++) o[j] = acc[j];
    }
    #pragma unroll
    for (int j = 0; j < 4; j++) acc[j] = make_float4(0.f, 0.f, 0.f, 0.f);
    qgemv64(ur, W3, q, acc);
    {
        float4* o = (float4*)Ru1 + (size_t)n * 16 + q * 4;
        #pragma unroll
        for (int j = 0; j < 4; j++) o[j] = acc[j];
    }
}

// ----------------------------- SPMM (spmm1) --------------------------------

__global__ __launch_bounds__(256) void spmm_k(const float2* __restrict__ xs,
                                              const int* __restrict__ srcs,
                                              const int* __restrict__ rowPtr,
                                              const float* __restrict__ dinv,
                                              const float* __restrict__ Wattn,
                                              float4* __restrict__ u,
                                              float2* __restrict__ us,
                                              float* __restrict__ tav, int N) {
    int node = (blockIdx.x * 256 + threadIdx.x) >> 6;
    if (node >= N) return;
    int lane = threadIdx.x & 63;
    int sub = lane >> 4;
    int q = lane & 15;
    int s0 = rowPtr[node], s1 = rowPtr[node + 1];
    float4 a0 = make_float4(0.f, 0.f, 0.f, 0.f);
    float4 a1 = a0, a2 = a0, a3 = a0;
    int i = s0 + sub;
    for (; i + 12 < s1; i += 16) {
        int sA = srcs[i];
        int sB = srcs[i + 4];
        int sC = srcs[i + 8];
        int sD = srcs[i + 12];
        float2 vA = xs[(size_t)sA * 16 + q];
        float2 vB = xs[(size_t)sB * 16 + q];
        float2 vC = xs[(size_t)sC * 16 + q];
        float2 vD = xs[(size_t)sD * 16 + q];
        acch4(a0, vA); acch4(a1, vB); acch4(a2, vC); acch4(a3, vD);
    }
    for (; i + 4 < s1; i += 8) {
        int sA = srcs[i];
        int sB = srcs[i + 4];
        float2 vA = xs[(size_t)sA * 16 + q];
        float2 vB = xs[(size_t)sB * 16 + q];
        acch4(a0, vA); acch4(a1, vB);
    }
    if (i < s1) {
        float2 vA = xs[(size_t)srcs[i] * 16 + q];
        acch4(a0, vA);
    }
    a0.x += a1.x + a2.x + a3.x;
    a0.y += a1.y + a2.y + a3.y;
    a0.z += a1.z + a2.z + a3.z;
    a0.w += a1.w + a2.w + a3.w;
    #pragma unroll
    for (int m = 16; m < 64; m <<= 1) {
        a0.x += __shfl_xor(a0.x, m, 64);
        a0.y += __shfl_xor(a0.y, m, 64);
        a0.z += __shfl_xor(a0.z, m, 64);
        a0.w += __shfl_xor(a0.w, m, 64);
    }
    if (sub == 0) {
        float di = dinv[node];
        float4 r = make_float4(a0.x * di, a0.y * di, a0.z * di, a0.w * di);
        u[(size_t)node * 16 + q] = r;
        us[(size_t)node * 16 + q] =
            pack_half4(r.x * di, r.y * di, r.z * di, r.w * di);
        float4 w = ((const float4*)Wattn)[q];
        float p = r.x * w.x + r.y * w.y + r.z * w.z + r.w * w.w;
        #pragma unroll
        for (int m = 1; m < 16; m <<= 1) p += __shfl_xor(p, m, 64);
        if (lane == 0) tav[node] = p;
    }
}

// ----------------------------- spmm2 (pure gather) --------------------------

__global__ __launch_bounds__(256) void spmm2_k(const float2* __restrict__ u1s,
                                               const int* __restrict__ srcs,
                                               const int* __restrict__ rowPtr,
                                               const float* __restrict__ dinv,
                                               const float* __restrict__ Wattn,
                                               float2* __restrict__ u2s,
                                               float* __restrict__ tbv, int N) {
    int node = (blockIdx.x * 256 + threadIdx.x) >> 6;
    if (node >= N) return;
    int lane = threadIdx.x & 63;
    int sub = lane >> 4;
    int q = lane & 15;
    int s0 = rowPtr[node], s1 = rowPtr[node + 1];
    float4 a0 = make_float4(0.f, 0.f, 0.f, 0.f);
    float4 a1 = a0, a2 = a0, a3 = a0;
    int i = s0 + sub;
    for (; i + 12 < s1; i += 16) {
        int sA = srcs[i];
        int sB = srcs[i + 4];
        int sC = srcs[i + 8];
        int sD = srcs[i + 12];
        float2 vA = u1s[(size_t)sA * 16 + q];
        float2 vB = u1s[(size_t)sB * 16 + q];
        float2 vC = u1s[(size_t)sC * 16 + q];
        float2 vD = u1s[(size_t)sD * 16 + q];
        acch4(a0, vA); acch4(a1, vB); acch4(a2, vC); acch4(a3, vD);
    }
    for (; i + 4 < s1; i += 8) {
        int sA = srcs[i];
        int sB = srcs[i + 4];
        float2 vA = u1s[(size_t)sA * 16 + q];
        float2 vB = u1s[(size_t)sB * 16 + q];
        acch4(a0, vA); acch4(a1, vB);
    }
    if (i < s1) {
        float2 vA = u1s[(size_t)srcs[i] * 16 + q];
        acch4(a0, vA);
    }
    a0.x += a1.x + a2.x + a3.x;
    a0.y += a1.y + a2.y + a3.y;
    a0.z += a1.z + a2.z + a3.z;
    a0.w += a1.w + a2.w + a3.w;
    #pragma unroll
    for (int m = 16; m < 64; m <<= 1) {
        a0.x += __shfl_xor(a0.x, m, 64);
        a0.y += __shfl_xor(a0.y, m, 64);
        a0.z += __shfl_xor(a0.z, m, 64);
        a0.w += __shfl_xor(a0.w, m, 64);
    }
    if (sub == 0) {
        float di = dinv[node];
        float4 r = make_float4(a0.x * di, a0.y * di, a0.z * di, a0.w * di);
        u2s[(size_t)node * 16 + q] = pack_half4(r.x, r.y, r.z, r.w);
        float4 w = ((const float4*)Wattn)[q];
        float p = r.x * w.x + r.y * w.y + r.z * w.z + r.w * w.w;
        #pragma unroll
        for (int m = 1; m < 16; m <<= 1) p += __shfl_xor(p, m, 64);
        if (lane == 0) tbv[node] = p;
    }
}

// ----------------------------- final (4 thr/node) ---------------------------

__global__ __launch_bounds__(256) void final_k(const float4* __restrict__ u2s4,
                                               const float* __restrict__ thv,
                                               const float* __restrict__ tav,
                                               const float* __restrict__ tbv,
                                               const float* __restrict__ battn,
                                               const float* __restrict__ Ph,
                                               const float* __restrict__ Pu1,
                                               const float* __restrict__ QhB,
                                               const float* __restrict__ Rh,
                                               const float* __restrict__ Ru1,
                                               const float* __restrict__ Rresb,
                                               const float* __restrict__ Wf1,
                                               const float* __restrict__ W3,
                                               const float* __restrict__ Wf2,
                                               const float* __restrict__ bf2,
                                               const float* __restrict__ W4,
                                               const float* __restrict__ b4,
                                               float2* __restrict__ out, int N) {
    int t = blockIdx.x * 256 + threadIdx.x;
    int n = t >> 2, q = t & 3;
    if (n >= N) return;
    float th = thv[n], ta = tav[n], tb = tbv[n], ba = battn[0];
    float s0 = 0.75f * th + 1.5f * ta + 0.75f * tb + ba;
    float s1 = 1.5f * th - 1.5f * tb + ba;
    float s2 = 0.75f * th - 1.5f * ta + 0.75f * tb + ba;
    float mx = fmaxf(s0, fmaxf(s1, s2));
    float e0 = expf(s0 - mx), e1 = expf(s1 - mx), e2 = expf(s2 - mx);
    float inv = 1.f / (e0 + e1 + e2);
    float w0 = e0 * inv, w1 = e1 * inv, w2 = e2 * inv;
    float ca = 0.75f * w0 + 1.5f * w1 + 0.75f * w2;
    float cb = 1.5f * (w0 - w2);
    float cc = 0.75f * w0 - 1.5f * w1 + 0.75f * w2;

    const float4* u2r = u2s4 + (size_t)n * 8;
    float4 acc[4];

    // P_u2 quarter
    #pragma unroll
    for (int j = 0; j < 4; j++) acc[j] = make_float4(0.f, 0.f, 0.f, 0.f);
    qgemv64h(u2r, Wf1, q, acc);

    const float4* Ph4 = (const float4*)Ph + (size_t)n * 16 + q * 4;
    const float4* Pu14 = (const float4*)Pu1 + (size_t)n * 16 + q * 4;
    const float4* Qh4 = (const float4*)QhB + (size_t)n * 16 + q * 4;
    const float4* Wf24 = (const float4*)Wf2 + q * 4;
    float fwacc = 0.f;
    #pragma unroll
    for (int j = 0; j < 4; j++) {
        float4 ph = Ph4[j], pu = Pu14[j], qh = Qh4[j], pw = acc[j];
        float4 tt;
        tt.x = fmaxf(ca * ph.x + cb * pu.x + cc * pw.x + qh.x, 0.f);
        tt.y = fmaxf(ca * ph.y + cb * pu.y + cc * pw.y + qh.y, 0.f);
        tt.z = fmaxf(ca * ph.z + cb * pu.z + cc * pw.z + qh.z, 0.f);
        tt.w = fmaxf(ca * ph.w + cb * pu.w + cc * pw.w + qh.w, 0.f);
        float4 wf = Wf24[j];
        fwacc += tt.x * wf.x + tt.y * wf.y + tt.z * wf.z + tt.w * wf.w;
    }
    fwacc += __shfl_xor(fwacc, 1, 4);
    fwacc += __shfl_xor(fwacc, 2, 4);
    float fw = 1.f / (1.f + expf(-(fwacc + bf2[0])));

    // R_u2 quarter
    #pragma unroll
    for (int j = 0; j < 4; j++) acc[j] = make_float4(0.f, 0.f, 0.f, 0.f);
    qgemv64h(u2r, W3, q, acc);

    const float4* Rh4 = (const float4*)Rh + (size_t)n * 16 + q * 4;
    const float4* Ru14 = (const float4*)Ru1 + (size_t)n * 16 + q * 4;
    const float4* Rb4 = (const float4*)Rresb + (size_t)n * 16 + q * 4;
    const float2* W42 = (const float2*)W4;
    float sa = 0.1f * fw;
    float sh = 1.f - fw;
    float l0 = 0.f, l1 = 0.f;
    #pragma unroll
    for (int j = 0; j < 4; j++) {
        float4 rh = Rh4[j], ru = Ru14[j], rb = Rb4[j], rw = acc[j];
        float4 g;
        g.x = fmaxf(sa * (ca * rh.x + cb * ru.x + cc * rw.x) + sh * rh.x + rb.x, 0.f);
        g.y = fmaxf(sa * (ca * rh.y + cb * ru.y + cc * rw.y) + sh * rh.y + rb.y, 0.f);
        g.z = fmaxf(sa * (ca * rh.z + cb * ru.z + cc * rw.z) + sh * rh.z + rb.z, 0.f);
        g.w = fmaxf(sa * (ca * rh.w + cb * ru.w + cc * rw.w) + sh * rh.w + rb.w, 0.f);
        int k0 = q * 16 + j * 4;
        float2 wa = W42[k0], wb = W42[k0 + 1], wc = W42[k0 + 2], wd = W42[k0 + 3];
        l0 += g.x * wa.x + g.y * wb.x + g.z * wc.x + g.w * wd.x;
        l1 += g.x * wa.y + g.y * wb.y + g.z * wc.y + g.w * wd.y;
    }
    l0 += __shfl_xor(l0, 1, 4);
    l0 += __shfl_xor(l0, 2, 4);
    l1 += __shfl_xor(l1, 1, 4);
    l1 += __shfl_xor(l1, 2, 4);
    if (q == 0) out[n] = make_float2(l0 + b4[0], l1 + b4[1]);
}

// ----------------------------- launch --------------------------------------

extern "C" void kernel_launch(void* const* d_in, const int* in_sizes, int n_in,
                              void* d_out, int out_size, void* d_ws, size_t ws_size,
                              hipStream_t stream) {
    const float* in_feat = (const float*)d_in[0];
    const int*   src     = (const int*)d_in[1];
    const int*   dst     = (const int*)d_in[2];
    const float* W1   = (const float*)d_in[3];
    const float* b1   = (const float*)d_in[4];
    const float* W2   = (const float*)d_in[5];
    const float* b2   = (const float*)d_in[6];
    const float* Wres = (const float*)d_in[7];
    const float* bres = (const float*)d_in[8];
    const float* Wattn = (const float*)d_in[9];
    const float* battn = (const float*)d_in[10];
    const float* Wf1  = (const float*)d_in[11];
    const float* bf1  = (const float*)d_in[12];
    const float* Wf2  = (const float*)d_in[13];
    const float* bf2  = (const float*)d_in[14];
    const float* W3   = (const float*)d_in[15];
    const float* b3   = (const float*)d_in[16];
    const float* W4   = (const float*)d_in[17];
    const float* b4   = (const float*)d_in[18];

    const int N = in_sizes[0] / 128;
    const int E = in_sizes[1];
    const int B = (N + BNODES - 1) >> BSHIFT;

    char* p = (char*)d_ws;
    auto take = [&](size_t bytes) -> char* {
        char* r = p;
        p += (bytes + 255) & ~(size_t)255;
        return r;
    };
    int*   bucketCount  = (int*)take((size_t)(B + 1) * 4);
    int*   bucketPtr    = (int*)take((size_t)(B + 1) * 4);
    int*   bucketCursor = (int*)take((size_t)(B + 1) * 4);
    int*   rowPtr       = (int*)take((size_t)(N + 1) * 4);
    float* dinv         = (float*)take((size_t)N * 4);
    int*   srcSorted    = (int*)take((size_t)E * 4);
    float* thv          = (float*)take((size_t)N * 4);
    float* tav          = (float*)take((size_t)N * 4);
    float* tbv          = (float*)take((size_t)N * 4);
    float* h1   = (float*)take((size_t)N * 256);   // also: ebuf, then Ph
    float* h    = (float*)take((size_t)N * 256);   // later reused as Ru1
    float* hs   = (float*)take((size_t)N * 128);   // f16 packed
    float* res  = (float*)take((size_t)N * 256);   // later reused as Pu1
    float* u1   = (float*)take((size_t)N * 256);
    float* u1s  = (float*)take((size_t)N * 128);   // f16 packed
    float* u2s  = (float*)take((size_t)N * 128);   // f16 packed
    float* QhB  = (float*)take((size_t)N * 256);
    float* Rh   = (float*)take((size_t)N * 256);
    float* Rresb= (float*)take((size_t)N * 256);
    int*   ebuf = (int*)h1;    // dead before dense1 writes h1 (stream order)
    float* Ph   = h1;          // h1 dead after dense2res reads it
    float* Pu1  = res;         // res dead after dense_post (Rresb consumed it)
    float* Ru1  = h;           // h dead after dense_post

    int eb = (E + CHUNK - 1) / CHUNK;
    int d1b = (N + D1_BLK - 1) / D1_BLK;
    int d2b = (N + D2_BLK - 1) / D2_BLK;
    int spb = (N * 64 + 255) / 256;
    int qb  = (N * 4 + 255) / 256;

    hipMemsetAsync(bucketCount, 0, (size_t)B * 4, stream);
    bucket_count_k<<<eb, 256, 0, stream>>>(dst, bucketCount, E, B);
    bucket_scan_k<<<1, 64, 0, stream>>>(bucketCount, bucketPtr, bucketCursor,
                                        rowPtr, B, N, E);
    bucket_scatter_k<<<eb, 256, 0, stream>>>(src, dst, bucketCursor, ebuf, E, B);
    csr_build_k<<<B, 256, 0, stream>>>(ebuf, bucketPtr, rowPtr, dinv, srcSorted, N);

    dense1_k<<<d1b, D1_BLK, 0, stream>>>(in_feat, W1, b1, h1, N);
    dense2res_k<<<d2b, D2_BLK, 0, stream>>>(h1, W2, b2, Wres, bres, Wattn, dinv,
                                            h, (float2*)hs, res, thv, N);

    dense_post_k<<<qb, 256, 0, stream>>>(h, res, Wf1, bf1, W3, b3,
                                         Ph, QhB, Rh, Rresb, N);

    spmm_k<<<spb, 256, 0, stream>>>((const float2*)hs, srcSorted, rowPtr, dinv,
                                    Wattn, (float4*)u1, (float2*)u1s, tav, N);

    dense_u1q_k<<<qb, 256, 0, stream>>>(u1, Wf1, W3, Pu1, Ru1, N);

    spmm2_k<<<spb, 256, 0, stream>>>((const float2*)u1s, srcSorted, rowPtr, dinv,
                                     Wattn, (float2*)u2s, tbv, N);

    final_k<<<qb, 256, 0, stream>>>((const float4*)u2s, thv, tav, tbv, battn,
                                    Ph, Pu1, QhB, Rh, Ru1, Rresb,
                                    Wf1, W3, Wf2, bf2, W4, b4,
                                    (float2*)d_out, N);
}

// Round 6
// 417.669 us; speedup vs baseline: 1.9179x; 1.9179x over previous
//
#include <hip/hip_runtime.h>
#include <hip/hip_fp16.h>
#include <math.h>

// ---------------------------------------------------------------------------
// ADCGNN amazon: N=50000, E=1.6M, IN=128, H=64, C=2, K=3
//
// R5: fp16 gather rows (bytes/lines halved; time flat).
// R6: 8-lane retile (instrs halved; worse, occ drop). REVERTED.
// R7: wave-private LDS + readlane GEMVs: tail 142->120us, VALU 74%. [BEST 394]
// R8/R9: algebraic expansion into extra dense passes: each thread/node GEMV
//     pass costs ~24us (only 782 waves exist) vs ~15us inline. REVERTED.
// R10 (this round): R3 base + gather concurrency. Evidence R0 vs R1: bytes
//     AND miss-lines halved -> time identical -> gather bound by outstanding
//     load INSTRUCTIONS per wave x latency. Fix: 8 independent gather chains
//     (2x in-flight instrs; VGPR ~48 keeps 8 waves/SIMD). Also split the
//     serial FMA chains in tail's GEMV loops (4 partial accumulators).
//
// Pipeline:
//   build: bucket_count -> bucket_scan -> bucket_scatter -> csr_build
//   dense1:    h1 = relu(X@W1+b1)
//   dense2res: h, hs=f16(h*dinv), res, th=h.Wattn
//   spmm1:     u1, u1s=f16(u1*dinv), ta      (8-chain gather)
//   tail:      wave/node: gather u2 (8-chain) -> softmax -> Wf1/Wf2 ->
//              W3 -> W4 -> logits. readlane GEMVs, split acc chains.
// ---------------------------------------------------------------------------

#define BSHIFT 7
#define BNODES 128
#define BMAX   512
#define EPT    32
#define CHUNK  (256 * EPT)
#define CAP    8192

__device__ __forceinline__ void fma4(float4& acc, float s, const float4 w) {
    acc.x += s * w.x; acc.y += s * w.y; acc.z += s * w.z; acc.w += s * w.w;
}

// wave-uniform broadcast of lane k's value via v_readlane (VALU, -> SGPR)
__device__ __forceinline__ float bcast(float v, int k) {
    return __uint_as_float(__builtin_amdgcn_readlane(__float_as_uint(v), k));
}

__device__ __forceinline__ float2 pack_half4(float x, float y, float z, float w) {
    union { __half2 h[2]; float2 f; } u;
    u.h[0] = __floats2half2_rn(x, y);
    u.h[1] = __floats2half2_rn(z, w);
    return u.f;
}

__device__ __forceinline__ void acch4(float4& a, float2 p) {
    union { float2 f; __half2 h[2]; } u; u.f = p;
    float2 lo = __half22float2(u.h[0]);
    float2 hi = __half22float2(u.h[1]);
    a.x += lo.x; a.y += lo.y; a.z += hi.x; a.w += hi.y;
}

// ----------------------------- graph build ---------------------------------

__global__ __launch_bounds__(256) void bucket_count_k(const int* __restrict__ dst,
                                                      int* __restrict__ bucketCount,
                                                      int E, int B) {
    __shared__ int cnt[BMAX];
    for (int i = threadIdx.x; i < B; i += 256) cnt[i] = 0;
    __syncthreads();
    int base = blockIdx.x * CHUNK;
    #pragma unroll
    for (int t = 0; t < EPT; t++) {
        int e = base + t * 256 + threadIdx.x;
        if (e < E) atomicAdd(&cnt[dst[e] >> BSHIFT], 1);
    }
    __syncthreads();
    for (int i = threadIdx.x; i < B; i += 256)
        if (cnt[i] > 0) atomicAdd(&bucketCount[i], cnt[i]);
}

__global__ __launch_bounds__(64) void bucket_scan_k(const int* __restrict__ bucketCount,
                                                    int* __restrict__ bucketPtr,
                                                    int* __restrict__ bucketCursor,
                                                    int* __restrict__ rowPtr,
                                                    int B, int N, int E) {
    int lane = threadIdx.x;
    const int PT = (BMAX + 63) / 64;
    int v[PT]; int s = 0;
    #pragma unroll
    for (int t = 0; t < PT; t++) {
        int i = lane * PT + t;
        v[t] = (i < B) ? bucketCount[i] : 0;
        s += v[t];
    }
    int x = s;
    #pragma unroll
    for (int off = 1; off < 64; off <<= 1) {
        int y = __shfl_up(x, off, 64);
        if (lane >= off) x += y;
    }
    int run = x - s;
    #pragma unroll
    for (int t = 0; t < PT; t++) {
        int i = lane * PT + t;
        if (i < B) { bucketPtr[i] = run; bucketCursor[i] = run; }
        run += v[t];
    }
    if (lane == 63) bucketPtr[B] = x;
    if (lane == 0) rowPtr[N] = E;
}

__global__ __launch_bounds__(256) void bucket_scatter_k(const int* __restrict__ src,
                                                        const int* __restrict__ dst,
                                                        int* __restrict__ bucketCursor,
                                                        int* __restrict__ ebuf,
                                                        int E, int B) {
    __shared__ int cnt[BMAX];
    __shared__ int base[BMAX];
    __shared__ int cur[BMAX];
    for (int i = threadIdx.x; i < B; i += 256) { cnt[i] = 0; cur[i] = 0; }
    __syncthreads();
    int cbase = blockIdx.x * CHUNK;
    int d[EPT];
    #pragma unroll
    for (int t = 0; t < EPT; t++) {
        int e = cbase + t * 256 + threadIdx.x;
        d[t] = (e < E) ? dst[e] : -1;
        if (d[t] >= 0) atomicAdd(&cnt[d[t] >> BSHIFT], 1);
    }
    __syncthreads();
    for (int i = threadIdx.x; i < B; i += 256)
        if (cnt[i] > 0) base[i] = atomicAdd(&bucketCursor[i], cnt[i]);
    __syncthreads();
    #pragma unroll
    for (int t = 0; t < EPT; t++) {
        int e = cbase + t * 256 + threadIdx.x;
        if (d[t] >= 0) {
            int b = d[t] >> BSHIFT;
            int c = atomicAdd(&cur[b], 1);
            int pack = (src[e] & 0xFFFF) | ((d[t] & (BNODES - 1)) << 16);
            ebuf[base[b] + c] = pack;
        }
    }
}

__global__ __launch_bounds__(256) void csr_build_k(const int* __restrict__ ebuf,
                                                   const int* __restrict__ bucketPtr,
                                                   int* __restrict__ rowPtr,
                                                   float* __restrict__ dinv,
                                                   int* __restrict__ srcSorted,
                                                   int N) {
    __shared__ int deg[BNODES];
    __shared__ int rp[BNODES + 1];
    __shared__ int cur[BNODES];
    __shared__ int stage[CAP];
    int b = blockIdx.x;
    int nodeBase = b << BSHIFT;
    int nNodes = min(BNODES, N - nodeBase);
    int eBase = bucketPtr[b];
    int eCnt = bucketPtr[b + 1] - eBase;
    for (int i = threadIdx.x; i < BNODES; i += 256) deg[i] = 0;
    __syncthreads();
    for (int i = threadIdx.x; i < eCnt; i += 256)
        atomicAdd(&deg[(ebuf[eBase + i] >> 16) & (BNODES - 1)], 1);
    __syncthreads();
    if (threadIdx.x < 64) {
        int lane = threadIdx.x;
        int d0 = deg[2 * lane], d1 = deg[2 * lane + 1];
        int s = d0 + d1;
        int x = s;
        #pragma unroll
        for (int off = 1; off < 64; off <<= 1) {
            int y = __shfl_up(x, off, 64);
            if (lane >= off) x += y;
        }
        int ex = x - s;
        rp[2 * lane] = ex;
        rp[2 * lane + 1] = ex + d0;
        cur[2 * lane] = ex;
        cur[2 * lane + 1] = ex + d0;
        if (lane == 63) rp[BNODES] = x;
    }
    __syncthreads();
    for (int j = threadIdx.x; j < nNodes; j += 256) {
        rowPtr[nodeBase + j] = eBase + rp[j];
        int dg = deg[j];
        dinv[nodeBase + j] = rsqrtf((float)(dg > 1 ? dg : 1));
    }
    if (eCnt <= CAP) {
        for (int i = threadIdx.x; i < eCnt; i += 256) {
            int p = ebuf[eBase + i];
            int ld = (p >> 16) & (BNODES - 1);
            int pos = atomicAdd(&cur[ld], 1);
            stage[pos] = p & 0xFFFF;
        }
        __syncthreads();
        for (int i = threadIdx.x; i < eCnt; i += 256)
            srcSorted[eBase + i] = stage[i];
    } else {
        for (int i = threadIdx.x; i < eCnt; i += 256) {
            int p = ebuf[eBase + i];
            int ld = (p >> 16) & (BNODES - 1);
            int pos = atomicAdd(&cur[ld], 1);
            srcSorted[eBase + pos] = p & 0xFFFF;
        }
    }
}

// ----------------------------- dense1 --------------------------------------

#define D1_BLK 128
#define D1_PAD 68

__global__ __launch_bounds__(D1_BLK) void dense1_k(const float* __restrict__ Xg,
                                                   const float* __restrict__ W1,
                                                   const float* __restrict__ b1,
                                                   float* __restrict__ h1, int N) {
    __shared__ float lds[D1_BLK * D1_PAD];
    int n0 = blockIdx.x * D1_BLK;
    int n = n0 + threadIdx.x;
    bool act = (n < N);
    const float4* W = (const float4*)W1;
    const float4* B = (const float4*)b1;
    float4 acc[16];
    #pragma unroll
    for (int j = 0; j < 16; j++) acc[j] = B[j];
    if (act) {
        const float4* X = (const float4*)Xg + (size_t)n * 32;
        float4 a = X[0];
        #pragma unroll 1
        for (int kc = 0; kc < 32; kc++) {
            float4 an = a;
            if (kc + 1 < 32) an = X[kc + 1];
            const float4* wrow = W + kc * 64;
            #pragma unroll
            for (int j = 0; j < 16; j++) {
                fma4(acc[j], a.x, wrow[j]);
                fma4(acc[j], a.y, wrow[16 + j]);
                fma4(acc[j], a.z, wrow[32 + j]);
                fma4(acc[j], a.w, wrow[48 + j]);
            }
            a = an;
        }
    }
    float* myrow = &lds[threadIdx.x * D1_PAD];
    #pragma unroll
    for (int j = 0; j < 16; j++) {
        float4 v = acc[j];
        *(float4*)&myrow[4 * j] = make_float4(fmaxf(v.x, 0.f), fmaxf(v.y, 0.f),
                                              fmaxf(v.z, 0.f), fmaxf(v.w, 0.f));
    }
    __syncthreads();
    float4* o4 = (float4*)h1;
    #pragma unroll
    for (int r = 0; r < 16; r++) {
        int idx = r * D1_BLK + threadIdx.x;
        int row = idx >> 4, col = idx & 15;
        int gn = n0 + row;
        if (gn < N) o4[(size_t)gn * 16 + col] = *(float4*)&lds[row * D1_PAD + col * 4];
    }
}

// ----------------------------- dense2res -----------------------------------

#define D2_BLK 128
#define D2_PAD 68

__global__ __launch_bounds__(D2_BLK) void dense2res_k(const float* __restrict__ h1,
                                                      const float* __restrict__ W2,
                                                      const float* __restrict__ b2,
                                                      const float* __restrict__ Wres,
                                                      const float* __restrict__ bres,
                                                      const float* __restrict__ Wattn,
                                                      const float* __restrict__ dinv,
                                                      float* __restrict__ hg,
                                                      float2* __restrict__ hs2,
                                                      float* __restrict__ resg,
                                                      float* __restrict__ thv, int N) {
    __shared__ float lds[D2_BLK * D2_PAD];
    int n0 = blockIdx.x * D2_BLK;
    int n = n0 + threadIdx.x;
    bool act = (n < N);
    const float4* W = (const float4*)W2;
    const float4* B = (const float4*)b2;
    float4 acc[16];
    #pragma unroll
    for (int j = 0; j < 16; j++) acc[j] = B[j];
    if (act) {
        const float4* X = (const float4*)h1 + (size_t)n * 16;
        float4 a = X[0];
        #pragma unroll 1
        for (int kc = 0; kc < 16; kc++) {
            float4 an = a;
            if (kc + 1 < 16) an = X[kc + 1];
            const float4* wrow = W + kc * 64;
            #pragma unroll
            for (int j = 0; j < 16; j++) {
                fma4(acc[j], a.x, wrow[j]);
                fma4(acc[j], a.y, wrow[16 + j]);
                fma4(acc[j], a.z, wrow[32 + j]);
                fma4(acc[j], a.w, wrow[48 + j]);
            }
            a = an;
        }
    }
    const float4* Wa = (const float4*)Wattn;
    float th = 0.f;
    float* myrow = &lds[threadIdx.x * D2_PAD];
    #pragma unroll
    for (int j = 0; j < 16; j++) {
        float4 v = acc[j];
        v.x = fmaxf(v.x, 0.f); v.y = fmaxf(v.y, 0.f);
        v.z = fmaxf(v.z, 0.f); v.w = fmaxf(v.w, 0.f);
        acc[j] = v;
        *(float4*)&myrow[4 * j] = v;
        float4 w = Wa[j];
        th += v.x * w.x + v.y * w.y + v.z * w.z + v.w * w.w;
    }
    if (act) thv[n] = th;
    __syncthreads();
    float4* h4 = (float4*)hg;
    #pragma unroll
    for (int r = 0; r < 16; r++) {
        int idx = r * D2_BLK + threadIdx.x;
        int row = idx >> 4, col = idx & 15;
        int gn = n0 + row;
        if (gn < N) {
            float4 v = *(float4*)&lds[row * D2_PAD + col * 4];
            h4[(size_t)gn * 16 + col] = v;
            float di = dinv[gn];
            hs2[(size_t)gn * 16 + col] =
                pack_half4(v.x * di, v.y * di, v.z * di, v.w * di);
        }
    }
    // res = h @ Wres + bres (h still in regs)
    const float4* WR = (const float4*)Wres;
    const float4* BR = (const float4*)bres;
    float4 acc2[16];
    #pragma unroll
    for (int j = 0; j < 16; j++) acc2[j] = BR[j];
    #pragma unroll 1
    for (int kc = 0; kc < 16; kc++) {
        float4 a2 = acc[kc];
        const float4* wrow = WR + kc * 64;
        #pragma unroll
        for (int j = 0; j < 16; j++) {
            fma4(acc2[j], a2.x, wrow[j]);
            fma4(acc2[j], a2.y, wrow[16 + j]);
            fma4(acc2[j], a2.z, wrow[32 + j]);
            fma4(acc2[j], a2.w, wrow[48 + j]);
        }
    }
    __syncthreads();
    #pragma unroll
    for (int j = 0; j < 16; j++) *(float4*)&myrow[4 * j] = acc2[j];
    __syncthreads();
    float4* r4 = (float4*)resg;
    #pragma unroll
    for (int r = 0; r < 16; r++) {
        int idx = r * D2_BLK + threadIdx.x;
        int row = idx >> 4, col = idx & 15;
        int gn = n0 + row;
        if (gn < N) r4[(size_t)gn * 16 + col] = *(float4*)&lds[row * D2_PAD + col * 4];
    }
}

// ----------------------------- SPMM (spmm1) --------------------------------
// Wave per node (4/block). 16 lanes per f16 row (float2 loads), 8 independent
// chains (2x in-flight VMEM instrs vs R3). fp32 accum.

__global__ __launch_bounds__(256) void spmm_k(const float2* __restrict__ xs,
                                              const int* __restrict__ srcs,
                                              const int* __restrict__ rowPtr,
                                              const float* __restrict__ dinv,
                                              const float* __restrict__ Wattn,
                                              float4* __restrict__ u,
                                              float2* __restrict__ us,
                                              float* __restrict__ tav, int N) {
    int node = (blockIdx.x * 256 + threadIdx.x) >> 6;
    if (node >= N) return;
    int lane = threadIdx.x & 63;
    int sub = lane >> 4;
    int q = lane & 15;
    int s0 = rowPtr[node], s1 = rowPtr[node + 1];
    float4 a0 = make_float4(0.f, 0.f, 0.f, 0.f);
    float4 a1 = a0, a2 = a0, a3 = a0, a4 = a0, a5 = a0, a6 = a0, a7 = a0;
    int i = s0 + sub;
    for (; i + 28 < s1; i += 32) {
        int sA = srcs[i];
        int sB = srcs[i + 4];
        int sC = srcs[i + 8];
        int sD = srcs[i + 12];
        int sE = srcs[i + 16];
        int sF = srcs[i + 20];
        int sG = srcs[i + 24];
        int sH = srcs[i + 28];
        float2 vA = xs[(size_t)sA * 16 + q];
        float2 vB = xs[(size_t)sB * 16 + q];
        float2 vC = xs[(size_t)sC * 16 + q];
        float2 vD = xs[(size_t)sD * 16 + q];
        float2 vE = xs[(size_t)sE * 16 + q];
        float2 vF = xs[(size_t)sF * 16 + q];
        float2 vG = xs[(size_t)sG * 16 + q];
        float2 vH = xs[(size_t)sH * 16 + q];
        acch4(a0, vA); acch4(a1, vB); acch4(a2, vC); acch4(a3, vD);
        acch4(a4, vE); acch4(a5, vF); acch4(a6, vG); acch4(a7, vH);
    }
    for (; i + 12 < s1; i += 16) {
        int sA = srcs[i];
        int sB = srcs[i + 4];
        int sC = srcs[i + 8];
        int sD = srcs[i + 12];
        float2 vA = xs[(size_t)sA * 16 + q];
        float2 vB = xs[(size_t)sB * 16 + q];
        float2 vC = xs[(size_t)sC * 16 + q];
        float2 vD = xs[(size_t)sD * 16 + q];
        acch4(a0, vA); acch4(a1, vB); acch4(a2, vC); acch4(a3, vD);
    }
    for (; i + 4 < s1; i += 8) {
        int sA = srcs[i];
        int sB = srcs[i + 4];
        float2 vA = xs[(size_t)sA * 16 + q];
        float2 vB = xs[(size_t)sB * 16 + q];
        acch4(a0, vA); acch4(a1, vB);
    }
    if (i < s1) {
        float2 vA = xs[(size_t)srcs[i] * 16 + q];
        acch4(a0, vA);
    }
    a0.x = ((a0.x + a1.x) + (a2.x + a3.x)) + ((a4.x + a5.x) + (a6.x + a7.x));
    a0.y = ((a0.y + a1.y) + (a2.y + a3.y)) + ((a4.y + a5.y) + (a6.y + a7.y));
    a0.z = ((a0.z + a1.z) + (a2.z + a3.z)) + ((a4.z + a5.z) + (a6.z + a7.z));
    a0.w = ((a0.w + a1.w) + (a2.w + a3.w)) + ((a4.w + a5.w) + (a6.w + a7.w));
    #pragma unroll
    for (int m = 16; m < 64; m <<= 1) {
        a0.x += __shfl_xor(a0.x, m, 64);
        a0.y += __shfl_xor(a0.y, m, 64);
        a0.z += __shfl_xor(a0.z, m, 64);
        a0.w += __shfl_xor(a0.w, m, 64);
    }
    if (sub == 0) {
        float di = dinv[node];
        float4 r = make_float4(a0.x * di, a0.y * di, a0.z * di, a0.w * di);
        u[(size_t)node * 16 + q] = r;
        us[(size_t)node * 16 + q] =
            pack_half4(r.x * di, r.y * di, r.z * di, r.w * di);
        float4 w = ((const float4*)Wattn)[q];
        float p = r.x * w.x + r.y * w.y + r.z * w.z + r.w * w.w;
        #pragma unroll
        for (int m = 1; m < 16; m <<= 1) p += __shfl_xor(p, m, 64);
        if (lane == 0) tav[node] = p;
    }
}

// ----------------------------- fused spmm2 + tail --------------------------
// Wave per node (4/block), no block barrier (wave-private LDS slice).
// 8-chain gather; readlane GEMVs with 4-way split accumulator chains.

#define TL_PAD 68

__global__ __launch_bounds__(256) void tail_k(const float2* __restrict__ u1s,
                                              const int* __restrict__ srcs,
                                              const int* __restrict__ rowPtr,
                                              const float* __restrict__ dinv,
                                              const float* __restrict__ hg,
                                              const float* __restrict__ u1g,
                                              const float* __restrict__ resg,
                                              const float* __restrict__ thv,
                                              const float* __restrict__ tav,
                                              const float* __restrict__ Wattn,
                                              const float* __restrict__ battn,
                                              const float* __restrict__ Wf1,
                                              const float* __restrict__ bf1,
                                              const float* __restrict__ Wf2,
                                              const float* __restrict__ bf2,
                                              const float* __restrict__ W3,
                                              const float* __restrict__ b3,
                                              const float* __restrict__ W4,
                                              const float* __restrict__ b4,
                                              float2* __restrict__ out, int N) {
    __shared__ float lds[4 * TL_PAD];
    int w = threadIdx.x >> 6;
    int lane = threadIdx.x & 63;
    int node = blockIdx.x * 4 + w;
    if (node >= N) return;
    int sub = lane >> 4, q = lane & 15;
    {
        int s0 = rowPtr[node], s1 = rowPtr[node + 1];
        float4 a0 = make_float4(0.f, 0.f, 0.f, 0.f);
        float4 a1 = a0, a2 = a0, a3 = a0, a4 = a0, a5 = a0, a6 = a0, a7 = a0;
        int i = s0 + sub;
        for (; i + 28 < s1; i += 32) {
            int sA = srcs[i];
            int sB = srcs[i + 4];
            int sC = srcs[i + 8];
            int sD = srcs[i + 12];
            int sE = srcs[i + 16];
            int sF = srcs[i + 20];
            int sG = srcs[i + 24];
            int sH = srcs[i + 28];
            float2 vA = u1s[(size_t)sA * 16 + q];
            float2 vB = u1s[(size_t)sB * 16 + q];
            float2 vC = u1s[(size_t)sC * 16 + q];
            float2 vD = u1s[(size_t)sD * 16 + q];
            float2 vE = u1s[(size_t)sE * 16 + q];
            float2 vF = u1s[(size_t)sF * 16 + q];
            float2 vG = u1s[(size_t)sG * 16 + q];
            float2 vH = u1s[(size_t)sH * 16 + q];
            acch4(a0, vA); acch4(a1, vB); acch4(a2, vC); acch4(a3, vD);
            acch4(a4, vE); acch4(a5, vF); acch4(a6, vG); acch4(a7, vH);
        }
        for (; i + 12 < s1; i += 16) {
            int sA = srcs[i];
            int sB = srcs[i + 4];
            int sC = srcs[i + 8];
            int sD = srcs[i + 12];
            float2 vA = u1s[(size_t)sA * 16 + q];
            float2 vB = u1s[(size_t)sB * 16 + q];
            float2 vC = u1s[(size_t)sC * 16 + q];
            float2 vD = u1s[(size_t)sD * 16 + q];
            acch4(a0, vA); acch4(a1, vB); acch4(a2, vC); acch4(a3, vD);
        }
        for (; i + 4 < s1; i += 8) {
            int sA = srcs[i];
            int sB = srcs[i + 4];
            float2 vA = u1s[(size_t)sA * 16 + q];
            float2 vB = u1s[(size_t)sB * 16 + q];
            acch4(a0, vA); acch4(a1, vB);
        }
        if (i < s1) {
            float2 vA = u1s[(size_t)srcs[i] * 16 + q];
            acch4(a0, vA);
        }
        a0.x = ((a0.x + a1.x) + (a2.x + a3.x)) + ((a4.x + a5.x) + (a6.x + a7.x));
        a0.y = ((a0.y + a1.y) + (a2.y + a3.y)) + ((a4.y + a5.y) + (a6.y + a7.y));
        a0.z = ((a0.z + a1.z) + (a2.z + a3.z)) + ((a4.z + a5.z) + (a6.z + a7.z));
        a0.w = ((a0.w + a1.w) + (a2.w + a3.w)) + ((a4.w + a5.w) + (a6.w + a7.w));
        #pragma unroll
        for (int m = 16; m < 64; m <<= 1) {
            a0.x += __shfl_xor(a0.x, m, 64);
            a0.y += __shfl_xor(a0.y, m, 64);
            a0.z += __shfl_xor(a0.z, m, 64);
            a0.w += __shfl_xor(a0.w, m, 64);
        }
        if (sub == 0) {
            float di = dinv[node];
            *(float4*)&lds[w * TL_PAD + q * 4] =
                make_float4(a0.x * di, a0.y * di, a0.z * di, a0.w * di);
        }
    }
    // wave-private LDS: same wave wrote it; lgkmcnt orders write->read.
    float u2j = lds[w * TL_PAD + lane];                  // feature j = lane
    float hj = hg[(size_t)node * 64 + lane];
    float u1j = u1g[(size_t)node * 64 + lane];
    float resj = resg[(size_t)node * 64 + lane];
    // tb = u2 . Wattn
    float tb = u2j * Wattn[lane];
    #pragma unroll
    for (int m = 1; m < 64; m <<= 1) tb += __shfl_xor(tb, m, 64);
    float th = thv[node], ta = tav[node], ba = battn[0];
    float s0 = 0.75f * th + 1.5f * ta + 0.75f * tb + ba;
    float s1 = 1.5f * th - 1.5f * tb + ba;
    float s2 = 0.75f * th - 1.5f * ta + 0.75f * tb + ba;
    float mx = fmaxf(s0, fmaxf(s1, s2));
    float e0 = expf(s0 - mx), e1 = expf(s1 - mx), e2 = expf(s2 - mx);
    float inv = 1.f / (e0 + e1 + e2);
    float w0 = e0 * inv, w1 = e1 * inv, w2 = e2 * inv;
    float ca = 0.75f * w0 + 1.5f * w1 + 0.75f * w2;
    float cb = 1.5f * (w0 - w2);
    float cc = 0.75f * w0 - 1.5f * w1 + 0.75f * w2;
    float afj = ca * hj + cb * u1j + cc * u2j;
    // t = relu([af | h] @ Wf1 + bf1)  (readlane GEMV, 4 split chains)
    float t0 = bf1[lane], t1 = 0.f, t2 = 0.f, t3 = 0.f;
    #pragma unroll 1
    for (int k = 0; k < 64; k += 4) {
        float a0_ = bcast(afj, k),     h0_ = bcast(hj, k);
        float a1_ = bcast(afj, k + 1), h1_ = bcast(hj, k + 1);
        float a2_ = bcast(afj, k + 2), h2_ = bcast(hj, k + 2);
        float a3_ = bcast(afj, k + 3), h3_ = bcast(hj, k + 3);
        t0 += a0_ * Wf1[k * 64 + lane]       + h0_ * Wf1[(64 + k) * 64 + lane];
        t1 += a1_ * Wf1[(k + 1) * 64 + lane] + h1_ * Wf1[(65 + k) * 64 + lane];
        t2 += a2_ * Wf1[(k + 2) * 64 + lane] + h2_ * Wf1[(66 + k) * 64 + lane];
        t3 += a3_ * Wf1[(k + 3) * 64 + lane] + h3_ * Wf1[(67 + k) * 64 + lane];
    }
    float t = fmaxf((t0 + t1) + (t2 + t3), 0.f);
    float fwacc = t * Wf2[lane];
    #pragma unroll
    for (int m = 1; m < 64; m <<= 1) fwacc += __shfl_xor(fwacc, m, 64);
    float fw = 1.f / (1.f + expf(-(fwacc + bf2[0])));
    // fused = 0.1*fw*af + (1-fw)*h + 0.8*res   (mean_fused == h exactly)
    float fj = 0.1f * fw * afj + (1.f - fw) * hj + 0.8f * resj;
    float g0 = b3[lane], g1 = 0.f, g2 = 0.f, g3 = 0.f;
    #pragma unroll 1
    for (int k = 0; k < 64; k += 4) {
        float f0_ = bcast(fj, k);
        float f1_ = bcast(fj, k + 1);
        float f2_ = bcast(fj, k + 2);
        float f3_ = bcast(fj, k + 3);
        g0 += f0_ * W3[k * 64 + lane];
        g1 += f1_ * W3[(k + 1) * 64 + lane];
        g2 += f2_ * W3[(k + 2) * 64 + lane];
        g3 += f3_ * W3[(k + 3) * 64 + lane];
    }
    float g = fmaxf((g0 + g1) + (g2 + g3), 0.f);
    float2 w4 = ((const float2*)W4)[lane];
    float l0 = g * w4.x, l1 = g * w4.y;
    #pragma unroll
    for (int m = 1; m < 64; m <<= 1) {
        l0 += __shfl_xor(l0, m, 64);
        l1 += __shfl_xor(l1, m, 64);
    }
    if (lane == 0) out[node] = make_float2(l0 + b4[0], l1 + b4[1]);
}

// ----------------------------- launch --------------------------------------

extern "C" void kernel_launch(void* const* d_in, const int* in_sizes, int n_in,
                              void* d_out, int out_size, void* d_ws, size_t ws_size,
                              hipStream_t stream) {
    const float* in_feat = (const float*)d_in[0];
    const int*   src     = (const int*)d_in[1];
    const int*   dst     = (const int*)d_in[2];
    const float* W1   = (const float*)d_in[3];
    const float* b1   = (const float*)d_in[4];
    const float* W2   = (const float*)d_in[5];
    const float* b2   = (const float*)d_in[6];
    const float* Wres = (const float*)d_in[7];
    const float* bres = (const float*)d_in[8];
    const float* Wattn = (const float*)d_in[9];
    const float* battn = (const float*)d_in[10];
    const float* Wf1  = (const float*)d_in[11];
    const float* bf1  = (const float*)d_in[12];
    const float* Wf2  = (const float*)d_in[13];
    const float* bf2  = (const float*)d_in[14];
    const float* W3   = (const float*)d_in[15];
    const float* b3   = (const float*)d_in[16];
    const float* W4   = (const float*)d_in[17];
    const float* b4   = (const float*)d_in[18];

    const int N = in_sizes[0] / 128;
    const int E = in_sizes[1];
    const int B = (N + BNODES - 1) >> BSHIFT;

    char* p = (char*)d_ws;
    auto take = [&](size_t bytes) -> char* {
        char* r = p;
        p += (bytes + 255) & ~(size_t)255;
        return r;
    };
    int*   bucketCount  = (int*)take((size_t)(B + 1) * 4);
    int*   bucketPtr    = (int*)take((size_t)(B + 1) * 4);
    int*   bucketCursor = (int*)take((size_t)(B + 1) * 4);
    int*   rowPtr       = (int*)take((size_t)(N + 1) * 4);
    float* dinv         = (float*)take((size_t)N * 4);
    int*   srcSorted    = (int*)take((size_t)E * 4);
    float* thv          = (float*)take((size_t)N * 4);
    float* tav          = (float*)take((size_t)N * 4);
    float* h1  = (float*)take((size_t)N * 256);
    float* h   = (float*)take((size_t)N * 256);
    float* hs  = (float*)take((size_t)N * 128);   // f16 packed, 64 halves/row
    float* res = (float*)take((size_t)N * 256);
    float* u1  = (float*)take((size_t)N * 256);
    float* u1s = (float*)take((size_t)N * 128);   // f16 packed
    int*   ebuf = (int*)h1;   // dead before dense1 writes h1 (stream order)

    int eb = (E + CHUNK - 1) / CHUNK;
    int d1b = (N + D1_BLK - 1) / D1_BLK;
    int d2b = (N + D2_BLK - 1) / D2_BLK;
    int spb = (N * 64 + 255) / 256;
    int tlb = (N + 3) / 4;

    hipMemsetAsync(bucketCount, 0, (size_t)B * 4, stream);
    bucket_count_k<<<eb, 256, 0, stream>>>(dst, bucketCount, E, B);
    bucket_scan_k<<<1, 64, 0, stream>>>(bucketCount, bucketPtr, bucketCursor,
                                        rowPtr, B, N, E);
    bucket_scatter_k<<<eb, 256, 0, stream>>>(src, dst, bucketCursor, ebuf, E, B);
    csr_build_k<<<B, 256, 0, stream>>>(ebuf, bucketPtr, rowPtr, dinv, srcSorted, N);

    dense1_k<<<d1b, D1_BLK, 0, stream>>>(in_feat, W1, b1, h1, N);
    dense2res_k<<<d2b, D2_BLK, 0, stream>>>(h1, W2, b2, Wres, bres, Wattn, dinv,
                                            h, (float2*)hs, res, thv, N);

    spmm_k<<<spb, 256, 0, stream>>>((const float2*)hs, srcSorted, rowPtr, dinv,
                                    Wattn, (float4*)u1, (float2*)u1s, tav, N);

    tail_k<<<tlb, 256, 0, stream>>>((const float2*)u1s, srcSorted, rowPtr, dinv,
                                    h, u1, res, thv, tav, Wattn, battn,
                                    Wf1, bf1, Wf2, bf2, W3, b3, W4, b4,
                                    (float2*)d_out, N);
}

// Round 7
// 391.150 us; speedup vs baseline: 2.0479x; 1.0678x over previous
//
#include <hip/hip_runtime.h>
#include <hip/hip_fp16.h>
#include <math.h>

// ---------------------------------------------------------------------------
// ADCGNN amazon: N=50000, E=1.6M, IN=128, H=64, C=2, K=3
//
// R5: fp16 gather rows (bytes/lines halved; time flat) -> not byte-bound.
// R6: 8-lane retile (instrs halved; worse, occ drop). REVERTED.
// R7: wave-private LDS + readlane GEMVs: tail 142->120us, VALU 74%. [394us]
// R8/R9: algebraic expansion -> starved dense passes. REVERTED.
// R10: 8 gather chains: occ 80->62 (VGPR 40), tail 142us. Per-wave ILP is
//      irrelevant; time ~ 1/waves. VALU arithmetic: ~600 wave-instr/node
//      x 195 nodes/CU ~ 97us = 74% x 120us -> tail is VALU-THROUGHPUT bound.
// R11 (this round): R3 gather (4-chain, occ 80%) + cut tail VALU: replace
//      192 v_readlane broadcasts with LDS-broadcast reads (ds_read_b128 at
//      wave-uniform addr; LDS pipe is idle, DS ops in-order per wave).
//      4-way split FMA chains retained.
//
// Pipeline:
//   build: bucket_count -> bucket_scan -> bucket_scatter -> csr_build
//   dense1:    h1 = relu(X@W1+b1)
//   dense2res: h, hs=f16(h*dinv), res, th=h.Wattn
//   spmm1:     u1, u1s=f16(u1*dinv), ta      (4-chain gather)
//   tail:      wave/node: gather u2 -> softmax -> Wf1/Wf2 -> W3 -> W4
//              LDS-broadcast GEMVs, no block barrier.
// ---------------------------------------------------------------------------

#define BSHIFT 7
#define BNODES 128
#define BMAX   512
#define EPT    32
#define CHUNK  (256 * EPT)
#define CAP    8192

__device__ __forceinline__ void fma4(float4& acc, float s, const float4 w) {
    acc.x += s * w.x; acc.y += s * w.y; acc.z += s * w.z; acc.w += s * w.w;
}

__device__ __forceinline__ float2 pack_half4(float x, float y, float z, float w) {
    union { __half2 h[2]; float2 f; } u;
    u.h[0] = __floats2half2_rn(x, y);
    u.h[1] = __floats2half2_rn(z, w);
    return u.f;
}

__device__ __forceinline__ void acch4(float4& a, float2 p) {
    union { float2 f; __half2 h[2]; } u; u.f = p;
    float2 lo = __half22float2(u.h[0]);
    float2 hi = __half22float2(u.h[1]);
    a.x += lo.x; a.y += lo.y; a.z += hi.x; a.w += hi.y;
}

// ----------------------------- graph build ---------------------------------

__global__ __launch_bounds__(256) void bucket_count_k(const int* __restrict__ dst,
                                                      int* __restrict__ bucketCount,
                                                      int E, int B) {
    __shared__ int cnt[BMAX];
    for (int i = threadIdx.x; i < B; i += 256) cnt[i] = 0;
    __syncthreads();
    int base = blockIdx.x * CHUNK;
    #pragma unroll
    for (int t = 0; t < EPT; t++) {
        int e = base + t * 256 + threadIdx.x;
        if (e < E) atomicAdd(&cnt[dst[e] >> BSHIFT], 1);
    }
    __syncthreads();
    for (int i = threadIdx.x; i < B; i += 256)
        if (cnt[i] > 0) atomicAdd(&bucketCount[i], cnt[i]);
}

__global__ __launch_bounds__(64) void bucket_scan_k(const int* __restrict__ bucketCount,
                                                    int* __restrict__ bucketPtr,
                                                    int* __restrict__ bucketCursor,
                                                    int* __restrict__ rowPtr,
                                                    int B, int N, int E) {
    int lane = threadIdx.x;
    const int PT = (BMAX + 63) / 64;
    int v[PT]; int s = 0;
    #pragma unroll
    for (int t = 0; t < PT; t++) {
        int i = lane * PT + t;
        v[t] = (i < B) ? bucketCount[i] : 0;
        s += v[t];
    }
    int x = s;
    #pragma unroll
    for (int off = 1; off < 64; off <<= 1) {
        int y = __shfl_up(x, off, 64);
        if (lane >= off) x += y;
    }
    int run = x - s;
    #pragma unroll
    for (int t = 0; t < PT; t++) {
        int i = lane * PT + t;
        if (i < B) { bucketPtr[i] = run; bucketCursor[i] = run; }
        run += v[t];
    }
    if (lane == 63) bucketPtr[B] = x;
    if (lane == 0) rowPtr[N] = E;
}

__global__ __launch_bounds__(256) void bucket_scatter_k(const int* __restrict__ src,
                                                        const int* __restrict__ dst,
                                                        int* __restrict__ bucketCursor,
                                                        int* __restrict__ ebuf,
                                                        int E, int B) {
    __shared__ int cnt[BMAX];
    __shared__ int base[BMAX];
    __shared__ int cur[BMAX];
    for (int i = threadIdx.x; i < B; i += 256) { cnt[i] = 0; cur[i] = 0; }
    __syncthreads();
    int cbase = blockIdx.x * CHUNK;
    int d[EPT];
    #pragma unroll
    for (int t = 0; t < EPT; t++) {
        int e = cbase + t * 256 + threadIdx.x;
        d[t] = (e < E) ? dst[e] : -1;
        if (d[t] >= 0) atomicAdd(&cnt[d[t] >> BSHIFT], 1);
    }
    __syncthreads();
    for (int i = threadIdx.x; i < B; i += 256)
        if (cnt[i] > 0) base[i] = atomicAdd(&bucketCursor[i], cnt[i]);
    __syncthreads();
    #pragma unroll
    for (int t = 0; t < EPT; t++) {
        int e = cbase + t * 256 + threadIdx.x;
        if (d[t] >= 0) {
            int b = d[t] >> BSHIFT;
            int c = atomicAdd(&cur[b], 1);
            int pack = (src[e] & 0xFFFF) | ((d[t] & (BNODES - 1)) << 16);
            ebuf[base[b] + c] = pack;
        }
    }
}

__global__ __launch_bounds__(256) void csr_build_k(const int* __restrict__ ebuf,
                                                   const int* __restrict__ bucketPtr,
                                                   int* __restrict__ rowPtr,
                                                   float* __restrict__ dinv,
                                                   int* __restrict__ srcSorted,
                                                   int N) {
    __shared__ int deg[BNODES];
    __shared__ int rp[BNODES + 1];
    __shared__ int cur[BNODES];
    __shared__ int stage[CAP];
    int b = blockIdx.x;
    int nodeBase = b << BSHIFT;
    int nNodes = min(BNODES, N - nodeBase);
    int eBase = bucketPtr[b];
    int eCnt = bucketPtr[b + 1] - eBase;
    for (int i = threadIdx.x; i < BNODES; i += 256) deg[i] = 0;
    __syncthreads();
    for (int i = threadIdx.x; i < eCnt; i += 256)
        atomicAdd(&deg[(ebuf[eBase + i] >> 16) & (BNODES - 1)], 1);
    __syncthreads();
    if (threadIdx.x < 64) {
        int lane = threadIdx.x;
        int d0 = deg[2 * lane], d1 = deg[2 * lane + 1];
        int s = d0 + d1;
        int x = s;
        #pragma unroll
        for (int off = 1; off < 64; off <<= 1) {
            int y = __shfl_up(x, off, 64);
            if (lane >= off) x += y;
        }
        int ex = x - s;
        rp[2 * lane] = ex;
        rp[2 * lane + 1] = ex + d0;
        cur[2 * lane] = ex;
        cur[2 * lane + 1] = ex + d0;
        if (lane == 63) rp[BNODES] = x;
    }
    __syncthreads();
    for (int j = threadIdx.x; j < nNodes; j += 256) {
        rowPtr[nodeBase + j] = eBase + rp[j];
        int dg = deg[j];
        dinv[nodeBase + j] = rsqrtf((float)(dg > 1 ? dg : 1));
    }
    if (eCnt <= CAP) {
        for (int i = threadIdx.x; i < eCnt; i += 256) {
            int p = ebuf[eBase + i];
            int ld = (p >> 16) & (BNODES - 1);
            int pos = atomicAdd(&cur[ld], 1);
            stage[pos] = p & 0xFFFF;
        }
        __syncthreads();
        for (int i = threadIdx.x; i < eCnt; i += 256)
            srcSorted[eBase + i] = stage[i];
    } else {
        for (int i = threadIdx.x; i < eCnt; i += 256) {
            int p = ebuf[eBase + i];
            int ld = (p >> 16) & (BNODES - 1);
            int pos = atomicAdd(&cur[ld], 1);
            srcSorted[eBase + pos] = p & 0xFFFF;
        }
    }
}

// ----------------------------- dense1 --------------------------------------

#define D1_BLK 128
#define D1_PAD 68

__global__ __launch_bounds__(D1_BLK) void dense1_k(const float* __restrict__ Xg,
                                                   const float* __restrict__ W1,
                                                   const float* __restrict__ b1,
                                                   float* __restrict__ h1, int N) {
    __shared__ float lds[D1_BLK * D1_PAD];
    int n0 = blockIdx.x * D1_BLK;
    int n = n0 + threadIdx.x;
    bool act = (n < N);
    const float4* W = (const float4*)W1;
    const float4* B = (const float4*)b1;
    float4 acc[16];
    #pragma unroll
    for (int j = 0; j < 16; j++) acc[j] = B[j];
    if (act) {
        const float4* X = (const float4*)Xg + (size_t)n * 32;
        float4 a = X[0];
        #pragma unroll 1
        for (int kc = 0; kc < 32; kc++) {
            float4 an = a;
            if (kc + 1 < 32) an = X[kc + 1];
            const float4* wrow = W + kc * 64;
            #pragma unroll
            for (int j = 0; j < 16; j++) {
                fma4(acc[j], a.x, wrow[j]);
                fma4(acc[j], a.y, wrow[16 + j]);
                fma4(acc[j], a.z, wrow[32 + j]);
                fma4(acc[j], a.w, wrow[48 + j]);
            }
            a = an;
        }
    }
    float* myrow = &lds[threadIdx.x * D1_PAD];
    #pragma unroll
    for (int j = 0; j < 16; j++) {
        float4 v = acc[j];
        *(float4*)&myrow[4 * j] = make_float4(fmaxf(v.x, 0.f), fmaxf(v.y, 0.f),
                                              fmaxf(v.z, 0.f), fmaxf(v.w, 0.f));
    }
    __syncthreads();
    float4* o4 = (float4*)h1;
    #pragma unroll
    for (int r = 0; r < 16; r++) {
        int idx = r * D1_BLK + threadIdx.x;
        int row = idx >> 4, col = idx & 15;
        int gn = n0 + row;
        if (gn < N) o4[(size_t)gn * 16 + col] = *(float4*)&lds[row * D1_PAD + col * 4];
    }
}

// ----------------------------- dense2res -----------------------------------

#define D2_BLK 128
#define D2_PAD 68

__global__ __launch_bounds__(D2_BLK) void dense2res_k(const float* __restrict__ h1,
                                                      const float* __restrict__ W2,
                                                      const float* __restrict__ b2,
                                                      const float* __restrict__ Wres,
                                                      const float* __restrict__ bres,
                                                      const float* __restrict__ Wattn,
                                                      const float* __restrict__ dinv,
                                                      float* __restrict__ hg,
                                                      float2* __restrict__ hs2,
                                                      float* __restrict__ resg,
                                                      float* __restrict__ thv, int N) {
    __shared__ float lds[D2_BLK * D2_PAD];
    int n0 = blockIdx.x * D2_BLK;
    int n = n0 + threadIdx.x;
    bool act = (n < N);
    const float4* W = (const float4*)W2;
    const float4* B = (const float4*)b2;
    float4 acc[16];
    #pragma unroll
    for (int j = 0; j < 16; j++) acc[j] = B[j];
    if (act) {
        const float4* X = (const float4*)h1 + (size_t)n * 16;
        float4 a = X[0];
        #pragma unroll 1
        for (int kc = 0; kc < 16; kc++) {
            float4 an = a;
            if (kc + 1 < 16) an = X[kc + 1];
            const float4* wrow = W + kc * 64;
            #pragma unroll
            for (int j = 0; j < 16; j++) {
                fma4(acc[j], a.x, wrow[j]);
                fma4(acc[j], a.y, wrow[16 + j]);
                fma4(acc[j], a.z, wrow[32 + j]);
                fma4(acc[j], a.w, wrow[48 + j]);
            }
            a = an;
        }
    }
    const float4* Wa = (const float4*)Wattn;
    float th = 0.f;
    float* myrow = &lds[threadIdx.x * D2_PAD];
    #pragma unroll
    for (int j = 0; j < 16; j++) {
        float4 v = acc[j];
        v.x = fmaxf(v.x, 0.f); v.y = fmaxf(v.y, 0.f);
        v.z = fmaxf(v.z, 0.f); v.w = fmaxf(v.w, 0.f);
        acc[j] = v;
        *(float4*)&myrow[4 * j] = v;
        float4 w = Wa[j];
        th += v.x * w.x + v.y * w.y + v.z * w.z + v.w * w.w;
    }
    if (act) thv[n] = th;
    __syncthreads();
    float4* h4 = (float4*)hg;
    #pragma unroll
    for (int r = 0; r < 16; r++) {
        int idx = r * D2_BLK + threadIdx.x;
        int row = idx >> 4, col = idx & 15;
        int gn = n0 + row;
        if (gn < N) {
            float4 v = *(float4*)&lds[row * D2_PAD + col * 4];
            h4[(size_t)gn * 16 + col] = v;
            float di = dinv[gn];
            hs2[(size_t)gn * 16 + col] =
                pack_half4(v.x * di, v.y * di, v.z * di, v.w * di);
        }
    }
    // res = h @ Wres + bres (h still in regs)
    const float4* WR = (const float4*)Wres;
    const float4* BR = (const float4*)bres;
    float4 acc2[16];
    #pragma unroll
    for (int j = 0; j < 16; j++) acc2[j] = BR[j];
    #pragma unroll 1
    for (int kc = 0; kc < 16; kc++) {
        float4 a2 = acc[kc];
        const float4* wrow = WR + kc * 64;
        #pragma unroll
        for (int j = 0; j < 16; j++) {
            fma4(acc2[j], a2.x, wrow[j]);
            fma4(acc2[j], a2.y, wrow[16 + j]);
            fma4(acc2[j], a2.z, wrow[32 + j]);
            fma4(acc2[j], a2.w, wrow[48 + j]);
        }
    }
    __syncthreads();
    #pragma unroll
    for (int j = 0; j < 16; j++) *(float4*)&myrow[4 * j] = acc2[j];
    __syncthreads();
    float4* r4 = (float4*)resg;
    #pragma unroll
    for (int r = 0; r < 16; r++) {
        int idx = r * D2_BLK + threadIdx.x;
        int row = idx >> 4, col = idx & 15;
        int gn = n0 + row;
        if (gn < N) r4[(size_t)gn * 16 + col] = *(float4*)&lds[row * D2_PAD + col * 4];
    }
}

// ----------------------------- SPMM (spmm1) --------------------------------
// Wave per node (4/block). 16 lanes per f16 row (float2 loads), 4 chains,
// fp32 accum. (R3 config: best measured occupancy/VALU balance.)

__global__ __launch_bounds__(256) void spmm_k(const float2* __restrict__ xs,
                                              const int* __restrict__ srcs,
                                              const int* __restrict__ rowPtr,
                                              const float* __restrict__ dinv,
                                              const float* __restrict__ Wattn,
                                              float4* __restrict__ u,
                                              float2* __restrict__ us,
                                              float* __restrict__ tav, int N) {
    int node = (blockIdx.x * 256 + threadIdx.x) >> 6;
    if (node >= N) return;
    int lane = threadIdx.x & 63;
    int sub = lane >> 4;
    int q = lane & 15;
    int s0 = rowPtr[node], s1 = rowPtr[node + 1];
    float4 a0 = make_float4(0.f, 0.f, 0.f, 0.f);
    float4 a1 = a0, a2 = a0, a3 = a0;
    int i = s0 + sub;
    for (; i + 12 < s1; i += 16) {
        int sA = srcs[i];
        int sB = srcs[i + 4];
        int sC = srcs[i + 8];
        int sD = srcs[i + 12];
        float2 vA = xs[(size_t)sA * 16 + q];
        float2 vB = xs[(size_t)sB * 16 + q];
        float2 vC = xs[(size_t)sC * 16 + q];
        float2 vD = xs[(size_t)sD * 16 + q];
        acch4(a0, vA); acch4(a1, vB); acch4(a2, vC); acch4(a3, vD);
    }
    for (; i + 4 < s1; i += 8) {
        int sA = srcs[i];
        int sB = srcs[i + 4];
        float2 vA = xs[(size_t)sA * 16 + q];
        float2 vB = xs[(size_t)sB * 16 + q];
        acch4(a0, vA); acch4(a1, vB);
    }
    if (i < s1) {
        float2 vA = xs[(size_t)srcs[i] * 16 + q];
        acch4(a0, vA);
    }
    a0.x += a1.x + a2.x + a3.x;
    a0.y += a1.y + a2.y + a3.y;
    a0.z += a1.z + a2.z + a3.z;
    a0.w += a1.w + a2.w + a3.w;
    #pragma unroll
    for (int m = 16; m < 64; m <<= 1) {
        a0.x += __shfl_xor(a0.x, m, 64);
        a0.y += __shfl_xor(a0.y, m, 64);
        a0.z += __shfl_xor(a0.z, m, 64);
        a0.w += __shfl_xor(a0.w, m, 64);
    }
    if (sub == 0) {
        float di = dinv[node];
        float4 r = make_float4(a0.x * di, a0.y * di, a0.z * di, a0.w * di);
        u[(size_t)node * 16 + q] = r;
        us[(size_t)node * 16 + q] =
            pack_half4(r.x * di, r.y * di, r.z * di, r.w * di);
        float4 w = ((const float4*)Wattn)[q];
        float p = r.x * w.x + r.y * w.y + r.z * w.z + r.w * w.w;
        #pragma unroll
        for (int m = 1; m < 16; m <<= 1) p += __shfl_xor(p, m, 64);
        if (lane == 0) tav[node] = p;
    }
}

// ----------------------------- fused spmm2 + tail --------------------------
// Wave per node (4/block), no block barrier (wave-private LDS slices; DS ops
// are in-order within a wave). GEMVs use LDS-broadcast reads (ds_read_b128
// at wave-uniform address) instead of v_readlane -> moves the 192 broadcasts
// off the VALU pipe. 4-way split FMA accumulator chains.

#define TL_PAD 68
#define BS_PAD 132   // per-wave broadcast slice: af[0:64] | h[64:128]

__global__ __launch_bounds__(256) void tail_k(const float2* __restrict__ u1s,
                                              const int* __restrict__ srcs,
                                              const int* __restrict__ rowPtr,
                                              const float* __restrict__ dinv,
                                              const float* __restrict__ hg,
                                              const float* __restrict__ u1g,
                                              const float* __restrict__ resg,
                                              const float* __restrict__ thv,
                                              const float* __restrict__ tav,
                                              const float* __restrict__ Wattn,
                                              const float* __restrict__ battn,
                                              const float* __restrict__ Wf1,
                                              const float* __restrict__ bf1,
                                              const float* __restrict__ Wf2,
                                              const float* __restrict__ bf2,
                                              const float* __restrict__ W3,
                                              const float* __restrict__ b3,
                                              const float* __restrict__ W4,
                                              const float* __restrict__ b4,
                                              float2* __restrict__ out, int N) {
    __shared__ float lds[4 * TL_PAD];
    __shared__ float bsl[4 * BS_PAD];
    int w = threadIdx.x >> 6;
    int lane = threadIdx.x & 63;
    int node = blockIdx.x * 4 + w;
    if (node >= N) return;
    int sub = lane >> 4, q = lane & 15;
    {
        int s0 = rowPtr[node], s1 = rowPtr[node + 1];
        float4 a0 = make_float4(0.f, 0.f, 0.f, 0.f);
        float4 a1 = a0, a2 = a0, a3 = a0;
        int i = s0 + sub;
        for (; i + 12 < s1; i += 16) {
            int sA = srcs[i];
            int sB = srcs[i + 4];
            int sC = srcs[i + 8];
            int sD = srcs[i + 12];
            float2 vA = u1s[(size_t)sA * 16 + q];
            float2 vB = u1s[(size_t)sB * 16 + q];
            float2 vC = u1s[(size_t)sC * 16 + q];
            float2 vD = u1s[(size_t)sD * 16 + q];
            acch4(a0, vA); acch4(a1, vB); acch4(a2, vC); acch4(a3, vD);
        }
        for (; i + 4 < s1; i += 8) {
            int sA = srcs[i];
            int sB = srcs[i + 4];
            float2 vA = u1s[(size_t)sA * 16 + q];
            float2 vB = u1s[(size_t)sB * 16 + q];
            acch4(a0, vA); acch4(a1, vB);
        }
        if (i < s1) {
            float2 vA = u1s[(size_t)srcs[i] * 16 + q];
            acch4(a0, vA);
        }
        a0.x += a1.x + a2.x + a3.x;
        a0.y += a1.y + a2.y + a3.y;
        a0.z += a1.z + a2.z + a3.z;
        a0.w += a1.w + a2.w + a3.w;
        #pragma unroll
        for (int m = 16; m < 64; m <<= 1) {
            a0.x += __shfl_xor(a0.x, m, 64);
            a0.y += __shfl_xor(a0.y, m, 64);
            a0.z += __shfl_xor(a0.z, m, 64);
            a0.w += __shfl_xor(a0.w, m, 64);
        }
        if (sub == 0) {
            float di = dinv[node];
            *(float4*)&lds[w * TL_PAD + q * 4] =
                make_float4(a0.x * di, a0.y * di, a0.z * di, a0.w * di);
        }
    }
    // wave-private LDS: same wave wrote it; DS ops in-order per wave.
    float u2j = lds[w * TL_PAD + lane];                  // feature j = lane
    float hj = hg[(size_t)node * 64 + lane];
    float u1j = u1g[(size_t)node * 64 + lane];
    float resj = resg[(size_t)node * 64 + lane];
    // tb = u2 . Wattn
    float tb = u2j * Wattn[lane];
    #pragma unroll
    for (int m = 1; m < 64; m <<= 1) tb += __shfl_xor(tb, m, 64);
    float th = thv[node], ta = tav[node], ba = battn[0];
    float s0 = 0.75f * th + 1.5f * ta + 0.75f * tb + ba;
    float s1 = 1.5f * th - 1.5f * tb + ba;
    float s2 = 0.75f * th - 1.5f * ta + 0.75f * tb + ba;
    float mx = fmaxf(s0, fmaxf(s1, s2));
    float e0 = expf(s0 - mx), e1 = expf(s1 - mx), e2 = expf(s2 - mx);
    float inv = 1.f / (e0 + e1 + e2);
    float w0 = e0 * inv, w1 = e1 * inv, w2 = e2 * inv;
    float ca = 0.75f * w0 + 1.5f * w1 + 0.75f * w2;
    float cb = 1.5f * (w0 - w2);
    float cc = 0.75f * w0 - 1.5f * w1 + 0.75f * w2;
    float afj = ca * hj + cb * u1j + cc * u2j;
    // stage af | h into the wave's broadcast slice (2 ds_writes)
    float* bsh = &bsl[w * BS_PAD];
    bsh[lane] = afj;
    bsh[64 + lane] = hj;
    // t = relu([af | h] @ Wf1 + bf1): LDS-broadcast GEMV, 4 split chains
    float t0 = bf1[lane], t1 = 0.f, t2 = 0.f, t3 = 0.f;
    #pragma unroll 1
    for (int k = 0; k < 64; k += 4) {
        float4 ak = *(const float4*)&bsh[k];        // broadcast ds_read_b128
        float4 hk = *(const float4*)&bsh[64 + k];
        t0 += ak.x * Wf1[(k + 0) * 64 + lane] + hk.x * Wf1[(64 + k) * 64 + lane];
        t1 += ak.y * Wf1[(k + 1) * 64 + lane] + hk.y * Wf1[(65 + k) * 64 + lane];
        t2 += ak.z * Wf1[(k + 2) * 64 + lane] + hk.z * Wf1[(66 + k) * 64 + lane];
        t3 += ak.w * Wf1[(k + 3) * 64 + lane] + hk.w * Wf1[(67 + k) * 64 + lane];
    }
    float t = fmaxf((t0 + t1) + (t2 + t3), 0.f);
    float fwacc = t * Wf2[lane];
    #pragma unroll
    for (int m = 1; m < 64; m <<= 1) fwacc += __shfl_xor(fwacc, m, 64);
    float fw = 1.f / (1.f + expf(-(fwacc + bf2[0])));
    // fused = 0.1*fw*af + (1-fw)*h + 0.8*res   (mean_fused == h exactly)
    float fj = 0.1f * fw * afj + (1.f - fw) * hj + 0.8f * resj;
    bsh[lane] = fj;   // overwrite af slot (in-order DS: reads above done)
    float g0 = b3[lane], g1 = 0.f, g2 = 0.f, g3 = 0.f;
    #pragma unroll 1
    for (int k = 0; k < 64; k += 4) {
        float4 fk = *(const float4*)&bsh[k];        // broadcast ds_read_b128
        g0 += fk.x * W3[(k + 0) * 64 + lane];
        g1 += fk.y * W3[(k + 1) * 64 + lane];
        g2 += fk.z * W3[(k + 2) * 64 + lane];
        g3 += fk.w * W3[(k + 3) * 64 + lane];
    }
    float g = fmaxf((g0 + g1) + (g2 + g3), 0.f);
    float2 w4 = ((const float2*)W4)[lane];
    float l0 = g * w4.x, l1 = g * w4.y;
    #pragma unroll
    for (int m = 1; m < 64; m <<= 1) {
        l0 += __shfl_xor(l0, m, 64);
        l1 += __shfl_xor(l1, m, 64);
    }
    if (lane == 0) out[node] = make_float2(l0 + b4[0], l1 + b4[1]);
}

// ----------------------------- launch --------------------------------------

extern "C" void kernel_launch(void* const* d_in, const int* in_sizes, int n_in,
                              void* d_out, int out_size, void* d_ws, size_t ws_size,
                              hipStream_t stream) {
    const float* in_feat = (const float*)d_in[0];
    const int*   src     = (const int*)d_in[1];
    const int*   dst     = (const int*)d_in[2];
    const float* W1   = (const float*)d_in[3];
    const float* b1   = (const float*)d_in[4];
    const float* W2   = (const float*)d_in[5];
    const float* b2   = (const float*)d_in[6];
    const float* Wres = (const float*)d_in[7];
    const float* bres = (const float*)d_in[8];
    const float* Wattn = (const float*)d_in[9];
    const float* battn = (const float*)d_in[10];
    const float* Wf1  = (const float*)d_in[11];
    const float* bf1  = (const float*)d_in[12];
    const float* Wf2  = (const float*)d_in[13];
    const float* bf2  = (const float*)d_in[14];
    const float* W3   = (const float*)d_in[15];
    const float* b3   = (const float*)d_in[16];
    const float* W4   = (const float*)d_in[17];
    const float* b4   = (const float*)d_in[18];

    const int N = in_sizes[0] / 128;
    const int E = in_sizes[1];
    const int B = (N + BNODES - 1) >> BSHIFT;

    char* p = (char*)d_ws;
    auto take = [&](size_t bytes) -> char* {
        char* r = p;
        p += (bytes + 255) & ~(size_t)255;
        return r;
    };
    int*   bucketCount  = (int*)take((size_t)(B + 1) * 4);
    int*   bucketPtr    = (int*)take((size_t)(B + 1) * 4);
    int*   bucketCursor = (int*)take((size_t)(B + 1) * 4);
    int*   rowPtr       = (int*)take((size_t)(N + 1) * 4);
    float* dinv         = (float*)take((size_t)N * 4);
    int*   srcSorted    = (int*)take((size_t)E * 4);
    float* thv          = (float*)take((size_t)N * 4);
    float* tav          = (float*)take((size_t)N * 4);
    float* h1  = (float*)take((size_t)N * 256);
    float* h   = (float*)take((size_t)N * 256);
    float* hs  = (float*)take((size_t)N * 128);   // f16 packed, 64 halves/row
    float* res = (float*)take((size_t)N * 256);
    float* u1  = (float*)take((size_t)N * 256);
    float* u1s = (float*)take((size_t)N * 128);   // f16 packed
    int*   ebuf = (int*)h1;   // dead before dense1 writes h1 (stream order)

    int eb = (E + CHUNK - 1) / CHUNK;
    int d1b = (N + D1_BLK - 1) / D1_BLK;
    int d2b = (N + D2_BLK - 1) / D2_BLK;
    int spb = (N * 64 + 255) / 256;
    int tlb = (N + 3) / 4;

    hipMemsetAsync(bucketCount, 0, (size_t)B * 4, stream);
    bucket_count_k<<<eb, 256, 0, stream>>>(dst, bucketCount, E, B);
    bucket_scan_k<<<1, 64, 0, stream>>>(bucketCount, bucketPtr, bucketCursor,
                                        rowPtr, B, N, E);
    bucket_scatter_k<<<eb, 256, 0, stream>>>(src, dst, bucketCursor, ebuf, E, B);
    csr_build_k<<<B, 256, 0, stream>>>(ebuf, bucketPtr, rowPtr, dinv, srcSorted, N);

    dense1_k<<<d1b, D1_BLK, 0, stream>>>(in_feat, W1, b1, h1, N);
    dense2res_k<<<d2b, D2_BLK, 0, stream>>>(h1, W2, b2, Wres, bres, Wattn, dinv,
                                            h, (float2*)hs, res, thv, N);

    spmm_k<<<spb, 256, 0, stream>>>((const float2*)hs, srcSorted, rowPtr, dinv,
                                    Wattn, (float4*)u1, (float2*)u1s, tav, N);

    tail_k<<<tlb, 256, 0, stream>>>((const float2*)u1s, srcSorted, rowPtr, dinv,
                                    h, u1, res, thv, tav, Wattn, battn,
                                    Wf1, bf1, Wf2, bf2, W3, b3, W4, b4,
                                    (float2*)d_out, N);
}

// Round 8
// 367.283 us; speedup vs baseline: 2.1810x; 1.0650x over previous
//
#include <hip/hip_runtime.h>
#include <hip/hip_fp16.h>
#include <math.h>

// ---------------------------------------------------------------------------
// ADCGNN amazon: N=50000, E=1.6M, IN=128, H=64, C=2, K=3
//
// R5: fp16 gather rows (bytes/lines halved; time flat) -> not byte-bound.
// R6: 8-lane retile -> worse (occ). REVERTED.
// R7: wave-private LDS + readlane GEMVs: tail 120us, VALU 74%. [394us]
// R8/R9: algebraic expansion -> starved dense passes. REVERTED.
// R10: 8 gather chains -> occ 62%, 142us. time ~ 1/waves.
// R11: LDS-broadcast GEMVs: VALU 74->59% but time FLAT (122us) [391us best]
//      -> second pipe saturated: 48KB fp32 weights/node thrash the 32KB L1.
// R12 (this round): fp16-packed Wf1/W3 (24KB, fits L1) + v_dot2_f32_f16
//      GEMVs (fp32 accum): halves GEMV VALU, weight loads, and weight bytes.
//
// Pipeline:
//   pack_w: Wf1,W3 -> fp16 pair-packed (once)
//   build: bucket_count -> bucket_scan -> bucket_scatter -> csr_build
//   dense1:    h1 = relu(X@W1+b1)
//   dense2res: h, hs=f16(h*dinv), res, th=h.Wattn
//   spmm1:     u1, u1s=f16(u1*dinv), ta      (4-chain gather)
//   tail:      wave/node: gather u2 -> softmax -> dot2-GEMVs -> logits
// ---------------------------------------------------------------------------

#define BSHIFT 7
#define BNODES 128
#define BMAX   512
#define EPT    32
#define CHUNK  (256 * EPT)
#define CAP    8192

typedef _Float16 h2v __attribute__((ext_vector_type(2)));

__device__ __forceinline__ h2v as_h2(unsigned int u) {
    union { unsigned int u; h2v h; } c; c.u = u; return c.h;
}

__device__ __forceinline__ void fma4(float4& acc, float s, const float4 w) {
    acc.x += s * w.x; acc.y += s * w.y; acc.z += s * w.z; acc.w += s * w.w;
}

__device__ __forceinline__ float2 pack_half4(float x, float y, float z, float w) {
    union { __half2 h[2]; float2 f; } u;
    u.h[0] = __floats2half2_rn(x, y);
    u.h[1] = __floats2half2_rn(z, w);
    return u.f;
}

__device__ __forceinline__ void acch4(float4& a, float2 p) {
    union { float2 f; __half2 h[2]; } u; u.f = p;
    float2 lo = __half22float2(u.h[0]);
    float2 hi = __half22float2(u.h[1]);
    a.x += lo.x; a.y += lo.y; a.z += hi.x; a.w += hi.y;
}

// ----------------------------- weight pack ---------------------------------
// Wf1h[kk*64+j] = half2(Wf1[2kk][j], Wf1[2kk+1][j])  kk<64 (covers [af|h])
// W3h [kk*64+j] = half2(W3 [2kk][j], W3 [2kk+1][j])  kk<32

__global__ __launch_bounds__(256) void pack_w_k(const float* __restrict__ Wf1,
                                                const float* __restrict__ W3,
                                                unsigned int* __restrict__ Wf1h,
                                                unsigned int* __restrict__ W3h) {
    int t = blockIdx.x * 256 + threadIdx.x;
    if (t < 64 * 64) {
        int kk = t >> 6, j = t & 63;
        union { __half2 h; unsigned int u; } c;
        c.h = __floats2half2_rn(Wf1[(2 * kk) * 64 + j], Wf1[(2 * kk + 1) * 64 + j]);
        Wf1h[t] = c.u;
    } else if (t < 64 * 64 + 32 * 64) {
        int r = t - 64 * 64;
        int kk = r >> 6, j = r & 63;
        union { __half2 h; unsigned int u; } c;
        c.h = __floats2half2_rn(W3[(2 * kk) * 64 + j], W3[(2 * kk + 1) * 64 + j]);
        W3h[r] = c.u;
    }
}

// ----------------------------- graph build ---------------------------------

__global__ __launch_bounds__(256) void bucket_count_k(const int* __restrict__ dst,
                                                      int* __restrict__ bucketCount,
                                                      int E, int B) {
    __shared__ int cnt[BMAX];
    for (int i = threadIdx.x; i < B; i += 256) cnt[i] = 0;
    __syncthreads();
    int base = blockIdx.x * CHUNK;
    #pragma unroll
    for (int t = 0; t < EPT; t++) {
        int e = base + t * 256 + threadIdx.x;
        if (e < E) atomicAdd(&cnt[dst[e] >> BSHIFT], 1);
    }
    __syncthreads();
    for (int i = threadIdx.x; i < B; i += 256)
        if (cnt[i] > 0) atomicAdd(&bucketCount[i], cnt[i]);
}

__global__ __launch_bounds__(64) void bucket_scan_k(const int* __restrict__ bucketCount,
                                                    int* __restrict__ bucketPtr,
                                                    int* __restrict__ bucketCursor,
                                                    int* __restrict__ rowPtr,
                                                    int B, int N, int E) {
    int lane = threadIdx.x;
    const int PT = (BMAX + 63) / 64;
    int v[PT]; int s = 0;
    #pragma unroll
    for (int t = 0; t < PT; t++) {
        int i = lane * PT + t;
        v[t] = (i < B) ? bucketCount[i] : 0;
        s += v[t];
    }
    int x = s;
    #pragma unroll
    for (int off = 1; off < 64; off <<= 1) {
        int y = __shfl_up(x, off, 64);
        if (lane >= off) x += y;
    }
    int run = x - s;
    #pragma unroll
    for (int t = 0; t < PT; t++) {
        int i = lane * PT + t;
        if (i < B) { bucketPtr[i] = run; bucketCursor[i] = run; }
        run += v[t];
    }
    if (lane == 63) bucketPtr[B] = x;
    if (lane == 0) rowPtr[N] = E;
}

__global__ __launch_bounds__(256) void bucket_scatter_k(const int* __restrict__ src,
                                                        const int* __restrict__ dst,
                                                        int* __restrict__ bucketCursor,
                                                        int* __restrict__ ebuf,
                                                        int E, int B) {
    __shared__ int cnt[BMAX];
    __shared__ int base[BMAX];
    __shared__ int cur[BMAX];
    for (int i = threadIdx.x; i < B; i += 256) { cnt[i] = 0; cur[i] = 0; }
    __syncthreads();
    int cbase = blockIdx.x * CHUNK;
    int d[EPT];
    #pragma unroll
    for (int t = 0; t < EPT; t++) {
        int e = cbase + t * 256 + threadIdx.x;
        d[t] = (e < E) ? dst[e] : -1;
        if (d[t] >= 0) atomicAdd(&cnt[d[t] >> BSHIFT], 1);
    }
    __syncthreads();
    for (int i = threadIdx.x; i < B; i += 256)
        if (cnt[i] > 0) base[i] = atomicAdd(&bucketCursor[i], cnt[i]);
    __syncthreads();
    #pragma unroll
    for (int t = 0; t < EPT; t++) {
        int e = cbase + t * 256 + threadIdx.x;
        if (d[t] >= 0) {
            int b = d[t] >> BSHIFT;
            int c = atomicAdd(&cur[b], 1);
            int pack = (src[e] & 0xFFFF) | ((d[t] & (BNODES - 1)) << 16);
            ebuf[base[b] + c] = pack;
        }
    }
}

__global__ __launch_bounds__(256) void csr_build_k(const int* __restrict__ ebuf,
                                                   const int* __restrict__ bucketPtr,
                                                   int* __restrict__ rowPtr,
                                                   float* __restrict__ dinv,
                                                   int* __restrict__ srcSorted,
                                                   int N) {
    __shared__ int deg[BNODES];
    __shared__ int rp[BNODES + 1];
    __shared__ int cur[BNODES];
    __shared__ int stage[CAP];
    int b = blockIdx.x;
    int nodeBase = b << BSHIFT;
    int nNodes = min(BNODES, N - nodeBase);
    int eBase = bucketPtr[b];
    int eCnt = bucketPtr[b + 1] - eBase;
    for (int i = threadIdx.x; i < BNODES; i += 256) deg[i] = 0;
    __syncthreads();
    for (int i = threadIdx.x; i < eCnt; i += 256)
        atomicAdd(&deg[(ebuf[eBase + i] >> 16) & (BNODES - 1)], 1);
    __syncthreads();
    if (threadIdx.x < 64) {
        int lane = threadIdx.x;
        int d0 = deg[2 * lane], d1 = deg[2 * lane + 1];
        int s = d0 + d1;
        int x = s;
        #pragma unroll
        for (int off = 1; off < 64; off <<= 1) {
            int y = __shfl_up(x, off, 64);
            if (lane >= off) x += y;
        }
        int ex = x - s;
        rp[2 * lane] = ex;
        rp[2 * lane + 1] = ex + d0;
        cur[2 * lane] = ex;
        cur[2 * lane + 1] = ex + d0;
        if (lane == 63) rp[BNODES] = x;
    }
    __syncthreads();
    for (int j = threadIdx.x; j < nNodes; j += 256) {
        rowPtr[nodeBase + j] = eBase + rp[j];
        int dg = deg[j];
        dinv[nodeBase + j] = rsqrtf((float)(dg > 1 ? dg : 1));
    }
    if (eCnt <= CAP) {
        for (int i = threadIdx.x; i < eCnt; i += 256) {
            int p = ebuf[eBase + i];
            int ld = (p >> 16) & (BNODES - 1);
            int pos = atomicAdd(&cur[ld], 1);
            stage[pos] = p & 0xFFFF;
        }
        __syncthreads();
        for (int i = threadIdx.x; i < eCnt; i += 256)
            srcSorted[eBase + i] = stage[i];
    } else {
        for (int i = threadIdx.x; i < eCnt; i += 256) {
            int p = ebuf[eBase + i];
            int ld = (p >> 16) & (BNODES - 1);
            int pos = atomicAdd(&cur[ld], 1);
            srcSorted[eBase + pos] = p & 0xFFFF;
        }
    }
}

// ----------------------------- dense1 --------------------------------------

#define D1_BLK 128
#define D1_PAD 68

__global__ __launch_bounds__(D1_BLK) void dense1_k(const float* __restrict__ Xg,
                                                   const float* __restrict__ W1,
                                                   const float* __restrict__ b1,
                                                   float* __restrict__ h1, int N) {
    __shared__ float lds[D1_BLK * D1_PAD];
    int n0 = blockIdx.x * D1_BLK;
    int n = n0 + threadIdx.x;
    bool act = (n < N);
    const float4* W = (const float4*)W1;
    const float4* B = (const float4*)b1;
    float4 acc[16];
    #pragma unroll
    for (int j = 0; j < 16; j++) acc[j] = B[j];
    if (act) {
        const float4* X = (const float4*)Xg + (size_t)n * 32;
        float4 a = X[0];
        #pragma unroll 1
        for (int kc = 0; kc < 32; kc++) {
            float4 an = a;
            if (kc + 1 < 32) an = X[kc + 1];
            const float4* wrow = W + kc * 64;
            #pragma unroll
            for (int j = 0; j < 16; j++) {
                fma4(acc[j], a.x, wrow[j]);
                fma4(acc[j], a.y, wrow[16 + j]);
                fma4(acc[j], a.z, wrow[32 + j]);
                fma4(acc[j], a.w, wrow[48 + j]);
            }
            a = an;
        }
    }
    float* myrow = &lds[threadIdx.x * D1_PAD];
    #pragma unroll
    for (int j = 0; j < 16; j++) {
        float4 v = acc[j];
        *(float4*)&myrow[4 * j] = make_float4(fmaxf(v.x, 0.f), fmaxf(v.y, 0.f),
                                              fmaxf(v.z, 0.f), fmaxf(v.w, 0.f));
    }
    __syncthreads();
    float4* o4 = (float4*)h1;
    #pragma unroll
    for (int r = 0; r < 16; r++) {
        int idx = r * D1_BLK + threadIdx.x;
        int row = idx >> 4, col = idx & 15;
        int gn = n0 + row;
        if (gn < N) o4[(size_t)gn * 16 + col] = *(float4*)&lds[row * D1_PAD + col * 4];
    }
}

// ----------------------------- dense2res -----------------------------------

#define D2_BLK 128
#define D2_PAD 68

__global__ __launch_bounds__(D2_BLK) void dense2res_k(const float* __restrict__ h1,
                                                      const float* __restrict__ W2,
                                                      const float* __restrict__ b2,
                                                      const float* __restrict__ Wres,
                                                      const float* __restrict__ bres,
                                                      const float* __restrict__ Wattn,
                                                      const float* __restrict__ dinv,
                                                      float* __restrict__ hg,
                                                      float2* __restrict__ hs2,
                                                      float* __restrict__ resg,
                                                      float* __restrict__ thv, int N) {
    __shared__ float lds[D2_BLK * D2_PAD];
    int n0 = blockIdx.x * D2_BLK;
    int n = n0 + threadIdx.x;
    bool act = (n < N);
    const float4* W = (const float4*)W2;
    const float4* B = (const float4*)b2;
    float4 acc[16];
    #pragma unroll
    for (int j = 0; j < 16; j++) acc[j] = B[j];
    if (act) {
        const float4* X = (const float4*)h1 + (size_t)n * 16;
        float4 a = X[0];
        #pragma unroll 1
        for (int kc = 0; kc < 16; kc++) {
            float4 an = a;
            if (kc + 1 < 16) an = X[kc + 1];
            const float4* wrow = W + kc * 64;
            #pragma unroll
            for (int j = 0; j < 16; j++) {
                fma4(acc[j], a.x, wrow[j]);
                fma4(acc[j], a.y, wrow[16 + j]);
                fma4(acc[j], a.z, wrow[32 + j]);
                fma4(acc[j], a.w, wrow[48 + j]);
            }
            a = an;
        }
    }
    const float4* Wa = (const float4*)Wattn;
    float th = 0.f;
    float* myrow = &lds[threadIdx.x * D2_PAD];
    #pragma unroll
    for (int j = 0; j < 16; j++) {
        float4 v = acc[j];
        v.x = fmaxf(v.x, 0.f); v.y = fmaxf(v.y, 0.f);
        v.z = fmaxf(v.z, 0.f); v.w = fmaxf(v.w, 0.f);
        acc[j] = v;
        *(float4*)&myrow[4 * j] = v;
        float4 w = Wa[j];
        th += v.x * w.x + v.y * w.y + v.z * w.z + v.w * w.w;
    }
    if (act) thv[n] = th;
    __syncthreads();
    float4* h4 = (float4*)hg;
    #pragma unroll
    for (int r = 0; r < 16; r++) {
        int idx = r * D2_BLK + threadIdx.x;
        int row = idx >> 4, col = idx & 15;
        int gn = n0 + row;
        if (gn < N) {
            float4 v = *(float4*)&lds[row * D2_PAD + col * 4];
            h4[(size_t)gn * 16 + col] = v;
            float di = dinv[gn];
            hs2[(size_t)gn * 16 + col] =
                pack_half4(v.x * di, v.y * di, v.z * di, v.w * di);
        }
    }
    // res = h @ Wres + bres (h still in regs)
    const float4* WR = (const float4*)Wres;
    const float4* BR = (const float4*)bres;
    float4 acc2[16];
    #pragma unroll
    for (int j = 0; j < 16; j++) acc2[j] = BR[j];
    #pragma unroll 1
    for (int kc = 0; kc < 16; kc++) {
        float4 a2 = acc[kc];
        const float4* wrow = WR + kc * 64;
        #pragma unroll
        for (int j = 0; j < 16; j++) {
            fma4(acc2[j], a2.x, wrow[j]);
            fma4(acc2[j], a2.y, wrow[16 + j]);
            fma4(acc2[j], a2.z, wrow[32 + j]);
            fma4(acc2[j], a2.w, wrow[48 + j]);
        }
    }
    __syncthreads();
    #pragma unroll
    for (int j = 0; j < 16; j++) *(float4*)&myrow[4 * j] = acc2[j];
    __syncthreads();
    float4* r4 = (float4*)resg;
    #pragma unroll
    for (int r = 0; r < 16; r++) {
        int idx = r * D2_BLK + threadIdx.x;
        int row = idx >> 4, col = idx & 15;
        int gn = n0 + row;
        if (gn < N) r4[(size_t)gn * 16 + col] = *(float4*)&lds[row * D2_PAD + col * 4];
    }
}

// ----------------------------- SPMM (spmm1) --------------------------------
// Wave per node (4/block). 16 lanes per f16 row (float2 loads), 4 chains,
// fp32 accum. (R3 config: best measured occupancy/VALU balance.)

__global__ __launch_bounds__(256) void spmm_k(const float2* __restrict__ xs,
                                              const int* __restrict__ srcs,
                                              const int* __restrict__ rowPtr,
                                              const float* __restrict__ dinv,
                                              const float* __restrict__ Wattn,
                                              float4* __restrict__ u,
                                              float2* __restrict__ us,
                                              float* __restrict__ tav, int N) {
    int node = (blockIdx.x * 256 + threadIdx.x) >> 6;
    if (node >= N) return;
    int lane = threadIdx.x & 63;
    int sub = lane >> 4;
    int q = lane & 15;
    int s0 = rowPtr[node], s1 = rowPtr[node + 1];
    float4 a0 = make_float4(0.f, 0.f, 0.f, 0.f);
    float4 a1 = a0, a2 = a0, a3 = a0;
    int i = s0 + sub;
    for (; i + 12 < s1; i += 16) {
        int sA = srcs[i];
        int sB = srcs[i + 4];
        int sC = srcs[i + 8];
        int sD = srcs[i + 12];
        float2 vA = xs[(size_t)sA * 16 + q];
        float2 vB = xs[(size_t)sB * 16 + q];
        float2 vC = xs[(size_t)sC * 16 + q];
        float2 vD = xs[(size_t)sD * 16 + q];
        acch4(a0, vA); acch4(a1, vB); acch4(a2, vC); acch4(a3, vD);
    }
    for (; i + 4 < s1; i += 8) {
        int sA = srcs[i];
        int sB = srcs[i + 4];
        float2 vA = xs[(size_t)sA * 16 + q];
        float2 vB = xs[(size_t)sB * 16 + q];
        acch4(a0, vA); acch4(a1, vB);
    }
    if (i < s1) {
        float2 vA = xs[(size_t)srcs[i] * 16 + q];
        acch4(a0, vA);
    }
    a0.x += a1.x + a2.x + a3.x;
    a0.y += a1.y + a2.y + a3.y;
    a0.z += a1.z + a2.z + a3.z;
    a0.w += a1.w + a2.w + a3.w;
    #pragma unroll
    for (int m = 16; m < 64; m <<= 1) {
        a0.x += __shfl_xor(a0.x, m, 64);
        a0.y += __shfl_xor(a0.y, m, 64);
        a0.z += __shfl_xor(a0.z, m, 64);
        a0.w += __shfl_xor(a0.w, m, 64);
    }
    if (sub == 0) {
        float di = dinv[node];
        float4 r = make_float4(a0.x * di, a0.y * di, a0.z * di, a0.w * di);
        u[(size_t)node * 16 + q] = r;
        us[(size_t)node * 16 + q] =
            pack_half4(r.x * di, r.y * di, r.z * di, r.w * di);
        float4 w = ((const float4*)Wattn)[q];
        float p = r.x * w.x + r.y * w.y + r.z * w.z + r.w * w.w;
        #pragma unroll
        for (int m = 1; m < 16; m <<= 1) p += __shfl_xor(p, m, 64);
        if (lane == 0) tav[node] = p;
    }
}

// ----------------------------- fused spmm2 + tail --------------------------
// Wave per node (4/block), no block barrier (wave-private LDS; DS in-order
// per wave). GEMVs: fp16 inputs staged in LDS (uniform 16B broadcast reads)
// x fp16 pair-packed weights via v_dot2_f32_f16, fp32 accumulate, 4 split
// chains. Weight working set 24KB -> fits 32KB L1.

#define TL_PAD 68
#define BS_HPAD 136   // _Float16 entries per wave slice (128 used)

__global__ __launch_bounds__(256) void tail_k(const float2* __restrict__ u1s,
                                              const int* __restrict__ srcs,
                                              const int* __restrict__ rowPtr,
                                              const float* __restrict__ dinv,
                                              const float* __restrict__ hg,
                                              const float* __restrict__ u1g,
                                              const float* __restrict__ resg,
                                              const float* __restrict__ thv,
                                              const float* __restrict__ tav,
                                              const float* __restrict__ Wattn,
                                              const float* __restrict__ battn,
                                              const unsigned int* __restrict__ Wf1h,
                                              const float* __restrict__ bf1,
                                              const float* __restrict__ Wf2,
                                              const float* __restrict__ bf2,
                                              const unsigned int* __restrict__ W3h,
                                              const float* __restrict__ b3,
                                              const float* __restrict__ W4,
                                              const float* __restrict__ b4,
                                              float2* __restrict__ out, int N) {
    __shared__ float lds[4 * TL_PAD];
    __shared__ _Float16 bsl[4 * BS_HPAD];
    int w = threadIdx.x >> 6;
    int lane = threadIdx.x & 63;
    int node = blockIdx.x * 4 + w;
    if (node >= N) return;
    int sub = lane >> 4, q = lane & 15;
    {
        int s0 = rowPtr[node], s1 = rowPtr[node + 1];
        float4 a0 = make_float4(0.f, 0.f, 0.f, 0.f);
        float4 a1 = a0, a2 = a0, a3 = a0;
        int i = s0 + sub;
        for (; i + 12 < s1; i += 16) {
            int sA = srcs[i];
            int sB = srcs[i + 4];
            int sC = srcs[i + 8];
            int sD = srcs[i + 12];
            float2 vA = u1s[(size_t)sA * 16 + q];
            float2 vB = u1s[(size_t)sB * 16 + q];
            float2 vC = u1s[(size_t)sC * 16 + q];
            float2 vD = u1s[(size_t)sD * 16 + q];
            acch4(a0, vA); acch4(a1, vB); acch4(a2, vC); acch4(a3, vD);
        }
        for (; i + 4 < s1; i += 8) {
            int sA = srcs[i];
            int sB = srcs[i + 4];
            float2 vA = u1s[(size_t)sA * 16 + q];
            float2 vB = u1s[(size_t)sB * 16 + q];
            acch4(a0, vA); acch4(a1, vB);
        }
        if (i < s1) {
            float2 vA = u1s[(size_t)srcs[i] * 16 + q];
            acch4(a0, vA);
        }
        a0.x += a1.x + a2.x + a3.x;
        a0.y += a1.y + a2.y + a3.y;
        a0.z += a1.z + a2.z + a3.z;
        a0.w += a1.w + a2.w + a3.w;
        #pragma unroll
        for (int m = 16; m < 64; m <<= 1) {
            a0.x += __shfl_xor(a0.x, m, 64);
            a0.y += __shfl_xor(a0.y, m, 64);
            a0.z += __shfl_xor(a0.z, m, 64);
            a0.w += __shfl_xor(a0.w, m, 64);
        }
        if (sub == 0) {
            float di = dinv[node];
            *(float4*)&lds[w * TL_PAD + q * 4] =
                make_float4(a0.x * di, a0.y * di, a0.z * di, a0.w * di);
        }
    }
    // wave-private LDS: same wave wrote it; DS ops in-order per wave.
    float u2j = lds[w * TL_PAD + lane];                  // feature j = lane
    float hj = hg[(size_t)node * 64 + lane];
    float u1j = u1g[(size_t)node * 64 + lane];
    float resj = resg[(size_t)node * 64 + lane];
    // tb = u2 . Wattn
    float tb = u2j * Wattn[lane];
    #pragma unroll
    for (int m = 1; m < 64; m <<= 1) tb += __shfl_xor(tb, m, 64);
    float th = thv[node], ta = tav[node], ba = battn[0];
    float s0 = 0.75f * th + 1.5f * ta + 0.75f * tb + ba;
    float s1 = 1.5f * th - 1.5f * tb + ba;
    float s2 = 0.75f * th - 1.5f * ta + 0.75f * tb + ba;
    float mx = fmaxf(s0, fmaxf(s1, s2));
    float e0 = expf(s0 - mx), e1 = expf(s1 - mx), e2 = expf(s2 - mx);
    float inv = 1.f / (e0 + e1 + e2);
    float w0 = e0 * inv, w1 = e1 * inv, w2 = e2 * inv;
    float ca = 0.75f * w0 + 1.5f * w1 + 0.75f * w2;
    float cb = 1.5f * (w0 - w2);
    float cc = 0.75f * w0 - 1.5f * w1 + 0.75f * w2;
    float afj = ca * hj + cb * u1j + cc * u2j;
    // stage af | h as fp16 into the wave's broadcast slice
    _Float16* bsh = &bsl[w * BS_HPAD];
    bsh[lane] = (_Float16)afj;
    bsh[64 + lane] = (_Float16)hj;
    // t = relu([af|h] @ Wf1 + bf1): dot2 GEMV over 64 packed pairs
    float t0 = bf1[lane], t1 = 0.f, t2 = 0.f, t3 = 0.f;
    #pragma unroll 1
    for (int kk = 0; kk < 64; kk += 4) {
        uint4 br = *(const uint4*)&bsh[2 * kk];   // pairs kk..kk+3 (16B)
        unsigned int w0_ = Wf1h[(kk + 0) * 64 + lane];
        unsigned int w1_ = Wf1h[(kk + 1) * 64 + lane];
        unsigned int w2_ = Wf1h[(kk + 2) * 64 + lane];
        unsigned int w3_ = Wf1h[(kk + 3) * 64 + lane];
        t0 = __builtin_amdgcn_fdot2(as_h2(br.x), as_h2(w0_), t0, false);
        t1 = __builtin_amdgcn_fdot2(as_h2(br.y), as_h2(w1_), t1, false);
        t2 = __builtin_amdgcn_fdot2(as_h2(br.z), as_h2(w2_), t2, false);
        t3 = __builtin_amdgcn_fdot2(as_h2(br.w), as_h2(w3_), t3, false);
    }
    float t = fmaxf((t0 + t1) + (t2 + t3), 0.f);
    float fwacc = t * Wf2[lane];
    #pragma unroll
    for (int m = 1; m < 64; m <<= 1) fwacc += __shfl_xor(fwacc, m, 64);
    float fw = 1.f / (1.f + expf(-(fwacc + bf2[0])));
    // fused = 0.1*fw*af + (1-fw)*h + 0.8*res   (mean_fused == h exactly)
    float fj = 0.1f * fw * afj + (1.f - fw) * hj + 0.8f * resj;
    bsh[lane] = (_Float16)fj;   // overwrite af slot (in-order DS)
    float g0 = b3[lane], g1 = 0.f, g2 = 0.f, g3 = 0.f;
    #pragma unroll 1
    for (int kk = 0; kk < 32; kk += 4) {
        uint4 br = *(const uint4*)&bsh[2 * kk];   // pairs kk..kk+3
        unsigned int w0_ = W3h[(kk + 0) * 64 + lane];
        unsigned int w1_ = W3h[(kk + 1) * 64 + lane];
        unsigned int w2_ = W3h[(kk + 2) * 64 + lane];
        unsigned int w3_ = W3h[(kk + 3) * 64 + lane];
        g0 = __builtin_amdgcn_fdot2(as_h2(br.x), as_h2(w0_), g0, false);
        g1 = __builtin_amdgcn_fdot2(as_h2(br.y), as_h2(w1_), g1, false);
        g2 = __builtin_amdgcn_fdot2(as_h2(br.z), as_h2(w2_), g2, false);
        g3 = __builtin_amdgcn_fdot2(as_h2(br.w), as_h2(w3_), g3, false);
    }
    float g = fmaxf((g0 + g1) + (g2 + g3), 0.f);
    float2 w4 = ((const float2*)W4)[lane];
    float l0 = g * w4.x, l1 = g * w4.y;
    #pragma unroll
    for (int m = 1; m < 64; m <<= 1) {
        l0 += __shfl_xor(l0, m, 64);
        l1 += __shfl_xor(l1, m, 64);
    }
    if (lane == 0) out[node] = make_float2(l0 + b4[0], l1 + b4[1]);
}

// ----------------------------- launch --------------------------------------

extern "C" void kernel_launch(void* const* d_in, const int* in_sizes, int n_in,
                              void* d_out, int out_size, void* d_ws, size_t ws_size,
                              hipStream_t stream) {
    const float* in_feat = (const float*)d_in[0];
    const int*   src     = (const int*)d_in[1];
    const int*   dst     = (const int*)d_in[2];
    const float* W1   = (const float*)d_in[3];
    const float* b1   = (const float*)d_in[4];
    const float* W2   = (const float*)d_in[5];
    const float* b2   = (const float*)d_in[6];
    const float* Wres = (const float*)d_in[7];
    const float* bres = (const float*)d_in[8];
    const float* Wattn = (const float*)d_in[9];
    const float* battn = (const float*)d_in[10];
    const float* Wf1  = (const float*)d_in[11];
    const float* bf1  = (const float*)d_in[12];
    const float* Wf2  = (const float*)d_in[13];
    const float* bf2  = (const float*)d_in[14];
    const float* W3   = (const float*)d_in[15];
    const float* b3   = (const float*)d_in[16];
    const float* W4   = (const float*)d_in[17];
    const float* b4   = (const float*)d_in[18];

    const int N = in_sizes[0] / 128;
    const int E = in_sizes[1];
    const int B = (N + BNODES - 1) >> BSHIFT;

    char* p = (char*)d_ws;
    auto take = [&](size_t bytes) -> char* {
        char* r = p;
        p += (bytes + 255) & ~(size_t)255;
        return r;
    };
    int*   bucketCount  = (int*)take((size_t)(B + 1) * 4);
    int*   bucketPtr    = (int*)take((size_t)(B + 1) * 4);
    int*   bucketCursor = (int*)take((size_t)(B + 1) * 4);
    int*   rowPtr       = (int*)take((size_t)(N + 1) * 4);
    float* dinv         = (float*)take((size_t)N * 4);
    int*   srcSorted    = (int*)take((size_t)E * 4);
    float* thv          = (float*)take((size_t)N * 4);
    float* tav          = (float*)take((size_t)N * 4);
    unsigned int* Wf1h  = (unsigned int*)take((size_t)64 * 64 * 4);
    unsigned int* W3h   = (unsigned int*)take((size_t)32 * 64 * 4);
    float* h1  = (float*)take((size_t)N * 256);
    float* h   = (float*)take((size_t)N * 256);
    float* hs  = (float*)take((size_t)N * 128);   // f16 packed, 64 halves/row
    float* res = (float*)take((size_t)N * 256);
    float* u1  = (float*)take((size_t)N * 256);
    float* u1s = (float*)take((size_t)N * 128);   // f16 packed
    int*   ebuf = (int*)h1;   // dead before dense1 writes h1 (stream order)

    int eb = (E + CHUNK - 1) / CHUNK;
    int d1b = (N + D1_BLK - 1) / D1_BLK;
    int d2b = (N + D2_BLK - 1) / D2_BLK;
    int spb = (N * 64 + 255) / 256;
    int tlb = (N + 3) / 4;

    pack_w_k<<<24, 256, 0, stream>>>(Wf1, W3, Wf1h, W3h);

    hipMemsetAsync(bucketCount, 0, (size_t)B * 4, stream);
    bucket_count_k<<<eb, 256, 0, stream>>>(dst, bucketCount, E, B);
    bucket_scan_k<<<1, 64, 0, stream>>>(bucketCount, bucketPtr, bucketCursor,
                                        rowPtr, B, N, E);
    bucket_scatter_k<<<eb, 256, 0, stream>>>(src, dst, bucketCursor, ebuf, E, B);
    csr_build_k<<<B, 256, 0, stream>>>(ebuf, bucketPtr, rowPtr, dinv, srcSorted, N);

    dense1_k<<<d1b, D1_BLK, 0, stream>>>(in_feat, W1, b1, h1, N);
    dense2res_k<<<d2b, D2_BLK, 0, stream>>>(h1, W2, b2, Wres, bres, Wattn, dinv,
                                            h, (float2*)hs, res, thv, N);

    spmm_k<<<spb, 256, 0, stream>>>((const float2*)hs, srcSorted, rowPtr, dinv,
                                    Wattn, (float4*)u1, (float2*)u1s, tav, N);

    tail_k<<<tlb, 256, 0, stream>>>((const float2*)u1s, srcSorted, rowPtr, dinv,
                                    h, u1, res, thv, tav, Wattn, battn,
                                    Wf1h, bf1, Wf2, bf2, W3h, b3, W4, b4,
                                    (float2*)d_out, N);
}